// Round 1
// baseline (1175.933 us; speedup 1.0000x reference)
//
#include <hip/hip_runtime.h>
#include <hip/hip_bf16.h>
#include <math.h>

// ---------- helpers ----------
__device__ __forceinline__ unsigned fmap(float f) {
    unsigned u = __float_as_uint(f);
    return (u & 0x80000000u) ? ~u : (u | 0x80000000u);
}
__device__ __forceinline__ float funmap(unsigned u) {
    return (u & 0x80000000u) ? __uint_as_float(u ^ 0x80000000u)
                             : __uint_as_float(~u);
}
__device__ __forceinline__ float lrelu(float x) { return x > 0.f ? x : 0.2f * x; }

// ---------- GEMM: C[N,M] = A[N,K] @ W[M,K]^T ----------
template<int M, int K>
__global__ __launch_bounds__(256) void gemm_tile(const float* __restrict__ A,
                                                 const float* __restrict__ W,
                                                 float* __restrict__ C, int N) {
    __shared__ float sW[M * (K + 1)];
    __shared__ float sA[32 * (K + 1)];
    int tid = threadIdx.x;
    for (int i = tid; i < M * K; i += 256) {
        int mr = i / K, kk = i - mr * K;
        sW[mr * (K + 1) + kk] = W[i];
    }
    int r0 = blockIdx.x * 32;
    for (int i = tid; i < 32 * K; i += 256) {
        int rr = i / K, kk = i - rr * K;
        int gr = r0 + rr;
        sA[rr * (K + 1) + kk] = (gr < N) ? A[(size_t)gr * K + kk] : 0.f;
    }
    __syncthreads();
    constexpr int PER = 32 * M / 256;
#pragma unroll
    for (int o = 0; o < PER; ++o) {
        int idx = o * 256 + tid;
        int rr = idx / M, mc = idx - rr * M;
        const float* pa = &sA[rr * (K + 1)];
        const float* pw = &sW[mc * (K + 1)];
        float acc = 0.f;
#pragma unroll 4
        for (int k = 0; k < K; ++k) acc += pa[k] * pw[k];
        int gr = r0 + rr;
        if (gr < N) C[(size_t)gr * M + mc] = acc;
    }
}

// ---------- per-node attention halves: as/ad [N,H] ----------
template<int H>
__global__ __launch_bounds__(256) void node_alpha(const float* __restrict__ h,
                                                  const float* __restrict__ att_s,
                                                  const float* __restrict__ att_d,
                                                  float* __restrict__ as_, float* __restrict__ ad_,
                                                  int N) {
    int w = (blockIdx.x * blockDim.x + threadIdx.x) >> 6;
    int lane = threadIdx.x & 63;
    if (w >= N) return;
#pragma unroll
    for (int hh = 0; hh < H; ++hh) {
        float v = h[(size_t)w * (H * 64) + hh * 64 + lane];
        float s = v * att_s[hh * 64 + lane];
        float d = v * att_d[hh * 64 + lane];
#pragma unroll
        for (int off = 32; off; off >>= 1) {
            s += __shfl_down(s, off);
            d += __shfl_down(d, off);
        }
        if (lane == 0) {
            as_[(size_t)w * H + hh] = s;
            ad_[(size_t)w * H + hh] = d;
        }
    }
}

// ---------- edge pass 1: segment max ----------
template<int H>
__global__ __launch_bounds__(256) void edge_max(const int* __restrict__ src,
                                                const int* __restrict__ dst,
                                                int E, int Et,
                                                const float* __restrict__ as_,
                                                const float* __restrict__ ad_,
                                                unsigned* __restrict__ m) {
    int e = blockIdx.x * blockDim.x + threadIdx.x;
    if (e >= Et) return;
    int s = (e < E) ? src[e] : (e - E);
    int d = (e < E) ? dst[e] : (e - E);
#pragma unroll
    for (int h = 0; h < H; ++h) {
        float sc = lrelu(as_[(size_t)s * H + h] + ad_[(size_t)d * H + h]);
        atomicMax(&m[(size_t)d * H + h], fmap(sc));
    }
}

// ---------- edge pass 2: segment sum of exp ----------
template<int H>
__global__ __launch_bounds__(256) void edge_expsum(const int* __restrict__ src,
                                                   const int* __restrict__ dst,
                                                   int E, int Et,
                                                   const float* __restrict__ as_,
                                                   const float* __restrict__ ad_,
                                                   const unsigned* __restrict__ m,
                                                   float* __restrict__ den) {
    int e = blockIdx.x * blockDim.x + threadIdx.x;
    if (e >= Et) return;
    int s = (e < E) ? src[e] : (e - E);
    int d = (e < E) ? dst[e] : (e - E);
#pragma unroll
    for (int h = 0; h < H; ++h) {
        float sc = lrelu(as_[(size_t)s * H + h] + ad_[(size_t)d * H + h]);
        float ex = expf(sc - funmap(m[(size_t)d * H + h]));
        atomicAdd(&den[(size_t)d * H + h], ex);
    }
}

// ---------- edge pass 3: weighted scatter-add, one wave per edge ----------
template<int HC, int H>
__global__ __launch_bounds__(256) void edge_agg(const int* __restrict__ src,
                                                const int* __restrict__ dst,
                                                int E, int Et,
                                                const float* __restrict__ as_,
                                                const float* __restrict__ ad_,
                                                const unsigned* __restrict__ m,
                                                const float* __restrict__ den,
                                                const float* __restrict__ h,
                                                float* __restrict__ agg) {
    int w = (blockIdx.x * blockDim.x + threadIdx.x) >> 6;
    int lane = threadIdx.x & 63;
    if (w >= Et) return;
    int s = (w < E) ? src[w] : (w - E);
    int d = (w < E) ? dst[w] : (w - E);
#pragma unroll
    for (int p = 0; p < HC / 64; ++p) {
        int j = p * 64 + lane;
        int hh = j >> 6;
        float sc = lrelu(as_[(size_t)s * H + hh] + ad_[(size_t)d * H + hh]);
        float alpha = expf(sc - funmap(m[(size_t)d * H + hh])) /
                      (den[(size_t)d * H + hh] + 1e-16f);
        atomicAdd(&agg[(size_t)d * HC + j], h[(size_t)s * HC + j] * alpha);
    }
}

// ---------- epilogues ----------
__global__ __launch_bounds__(256) void finalize_elu(float* __restrict__ a,
                                                    const float* __restrict__ b,
                                                    int total) {
    int i = blockIdx.x * blockDim.x + threadIdx.x;
    if (i >= total) return;
    float v = a[i] + b[i & 127];
    a[i] = v > 0.f ? v : expm1f(v);
}

__global__ __launch_bounds__(256) void finalize_bias(const float* __restrict__ a,
                                                     const float* __restrict__ b,
                                                     float* __restrict__ o, int total) {
    int i = blockIdx.x * blockDim.x + threadIdx.x;
    if (i >= total) return;
    o[i] = a[i] + b[i & 63];
}

extern "C" void kernel_launch(void* const* d_in, const int* in_sizes, int n_in,
                              void* d_out, int out_size, void* d_ws, size_t ws_size,
                              hipStream_t stream) {
    const float* x   = (const float*)d_in[0];
    const int*   ei  = (const int*)d_in[1];
    const float* W1  = (const float*)d_in[2];
    const float* a1s = (const float*)d_in[3];
    const float* a1d = (const float*)d_in[4];
    const float* b1  = (const float*)d_in[5];
    const float* W2  = (const float*)d_in[6];
    const float* a2s = (const float*)d_in[7];
    const float* a2d = (const float*)d_in[8];
    const float* b2  = (const float*)d_in[9];
    float* out = (float*)d_out;

    int N  = in_sizes[0] / 128;
    int E  = in_sizes[1] / 2;
    int Et = E + N;
    const int* src = ei;
    const int* dst = ei + E;

    float* h1   = (float*)d_ws;                 // N*128
    float* agg1 = h1 + (size_t)N * 128;         // N*128 (in-place ELU -> act1)
    float* as1  = agg1 + (size_t)N * 128;       // N*2
    float* ad1  = as1 + (size_t)N * 2;          // N*2
    unsigned* m1 = (unsigned*)(ad1 + (size_t)N * 2); // N*2
    float* den1 = (float*)(m1 + (size_t)N * 2); // N*2
    float* as2  = den1 + (size_t)N * 2;         // N
    float* ad2  = as2 + N;                      // N
    unsigned* m2 = (unsigned*)(ad2 + N);        // N
    float* den2 = (float*)(m2 + N);             // N
    float* h2   = h1;                           // reuse: N*64
    float* agg2 = h1 + (size_t)N * 64;          // reuse: N*64

    hipMemsetAsync(agg1, 0, (size_t)N * 128 * 4, stream);
    hipMemsetAsync(m1,   0, (size_t)N * 2 * 4, stream);
    hipMemsetAsync(den1, 0, (size_t)N * 2 * 4, stream);
    hipMemsetAsync(m2,   0, (size_t)N * 4, stream);
    hipMemsetAsync(den2, 0, (size_t)N * 4, stream);

    // ---- layer 1 ----
    gemm_tile<128, 128><<<(N + 31) / 32, 256, 0, stream>>>(x, W1, h1, N);
    node_alpha<2><<<(N + 3) / 4, 256, 0, stream>>>(h1, a1s, a1d, as1, ad1, N);
    edge_max<2><<<(Et + 255) / 256, 256, 0, stream>>>(src, dst, E, Et, as1, ad1, m1);
    edge_expsum<2><<<(Et + 255) / 256, 256, 0, stream>>>(src, dst, E, Et, as1, ad1, m1, den1);
    edge_agg<128, 2><<<(Et + 3) / 4, 256, 0, stream>>>(src, dst, E, Et, as1, ad1, m1, den1, h1, agg1);
    finalize_elu<<<((size_t)N * 128 + 255) / 256, 256, 0, stream>>>(agg1, b1, N * 128);

    // ---- layer 2 ----
    hipMemsetAsync(agg2, 0, (size_t)N * 64 * 4, stream);
    gemm_tile<64, 128><<<(N + 31) / 32, 256, 0, stream>>>(agg1, W2, h2, N);
    node_alpha<1><<<(N + 3) / 4, 256, 0, stream>>>(h2, a2s, a2d, as2, ad2, N);
    edge_max<1><<<(Et + 255) / 256, 256, 0, stream>>>(src, dst, E, Et, as2, ad2, m2);
    edge_expsum<1><<<(Et + 255) / 256, 256, 0, stream>>>(src, dst, E, Et, as2, ad2, m2, den2);
    edge_agg<64, 1><<<(Et + 3) / 4, 256, 0, stream>>>(src, dst, E, Et, as2, ad2, m2, den2, h2, agg2);
    finalize_bias<<<((size_t)N * 64 + 255) / 256, 256, 0, stream>>>(agg2, b2, out, N * 64);
}

// Round 2
// 465.056 us; speedup vs baseline: 2.5286x; 2.5286x over previous
//
#include <hip/hip_runtime.h>
#include <hip/hip_bf16.h>
#include <math.h>

__device__ __forceinline__ float lrelu(float x) { return x > 0.f ? x : 0.2f * x; }
__device__ __forceinline__ float wred_max(float v) {
#pragma unroll
    for (int o = 32; o; o >>= 1) v = fmaxf(v, __shfl_xor(v, o));
    return v;
}
__device__ __forceinline__ float wred_sum(float v) {
#pragma unroll
    for (int o = 32; o; o >>= 1) v += __shfl_xor(v, o);
    return v;
}

// ---------------- CSR build ----------------
__global__ __launch_bounds__(256) void count_deg(const int* __restrict__ dst,
                                                 int E, int Et, int* __restrict__ deg) {
    int e = blockIdx.x * blockDim.x + threadIdx.x;
    if (e >= Et) return;
    int d = (e < E) ? dst[e] : (e - E);
    atomicAdd(&deg[d], 1);
}

// single-block exclusive scan (N up to a few hundred K is fine)
__global__ __launch_bounds__(256) void scan_deg(const int* __restrict__ deg,
                                                int* __restrict__ rowptr, int N) {
    __shared__ int wsum[4];
    __shared__ int s_carry;
    int tid = threadIdx.x, lane = tid & 63, w = tid >> 6;
    if (tid == 0) s_carry = 0;
    __syncthreads();
    for (int base = 0; base < N; base += 256) {
        int idx = base + tid;
        int v = (idx < N) ? deg[idx] : 0;
        int incl = v;
#pragma unroll
        for (int off = 1; off < 64; off <<= 1) {
            int t = __shfl_up(incl, off);
            if (lane >= off) incl += t;
        }
        if (lane == 63) wsum[w] = incl;
        __syncthreads();
        int wpre = 0;
        for (int k = 0; k < w; ++k) wpre += wsum[k];
        int carry = s_carry;
        if (idx < N) rowptr[idx] = carry + wpre + incl - v;
        __syncthreads();
        if (tid == 255) s_carry = carry + wpre + incl;
        __syncthreads();
    }
    if (tid == 0) rowptr[N] = s_carry;
}

__global__ __launch_bounds__(256) void scatter_edges(const int* __restrict__ src,
                                                     const int* __restrict__ dst,
                                                     int E, int Et,
                                                     const int* __restrict__ rowptr,
                                                     int* __restrict__ cursor,
                                                     int* __restrict__ srcs) {
    int e = blockIdx.x * blockDim.x + threadIdx.x;
    if (e >= Et) return;
    int d = (e < E) ? dst[e] : (e - E);
    int s = (e < E) ? src[e] : (e - E);
    int pos = atomicAdd(&cursor[d], 1);
    srcs[rowptr[d] + pos] = s;
}

// ---------------- GEMM: C[N,M] = A[N,128] @ W[M,128]^T, reg-tiled ----------------
template<int M>
__global__ __launch_bounds__(256) void gemm_rt(const float* __restrict__ A,
                                               const float* __restrict__ W,
                                               float* __restrict__ C, int N) {
    constexpr int KB = 64;
    constexpr int LD = KB + 4;       // float row stride, 16B-aligned
    constexpr int CI = M / 32;       // cols per thread
    __shared__ float sA[32 * LD];
    __shared__ float sW[M * LD];
    int tid = threadIdx.x;
    int tx = tid & 31, ty = tid >> 5;
    int r0 = blockIdx.x * 32;
    float acc[4][CI] = {};
    for (int kt = 0; kt < 128; kt += KB) {
        for (int v = tid; v < 32 * (KB / 4); v += 256) {
            int rr = v / (KB / 4), kk = (v % (KB / 4)) * 4;
            float4 val = make_float4(0, 0, 0, 0);
            if (r0 + rr < N) val = *(const float4*)&A[(size_t)(r0 + rr) * 128 + kt + kk];
            *(float4*)&sA[rr * LD + kk] = val;
        }
        for (int v = tid; v < M * (KB / 4); v += 256) {
            int mr = v / (KB / 4), kk = (v % (KB / 4)) * 4;
            *(float4*)&sW[mr * LD + kk] = *(const float4*)&W[(size_t)mr * 128 + kt + kk];
        }
        __syncthreads();
#pragma unroll
        for (int k = 0; k < KB; k += 4) {
            float4 a4[4], w4[CI];
#pragma unroll
            for (int j = 0; j < 4; ++j) a4[j] = *(float4*)&sA[(ty + 8 * j) * LD + k];
#pragma unroll
            for (int i = 0; i < CI; ++i) w4[i] = *(float4*)&sW[(tx + 32 * i) * LD + k];
#pragma unroll
            for (int j = 0; j < 4; ++j)
#pragma unroll
                for (int i = 0; i < CI; ++i)
                    acc[j][i] += a4[j].x * w4[i].x + a4[j].y * w4[i].y +
                                 a4[j].z * w4[i].z + a4[j].w * w4[i].w;
        }
        __syncthreads();
    }
#pragma unroll
    for (int j = 0; j < 4; ++j) {
        int gr = r0 + ty + 8 * j;
        if (gr < N)
#pragma unroll
            for (int i = 0; i < CI; ++i)
                C[(size_t)gr * M + tx + 32 * i] = acc[j][i];
    }
}

// ---------------- per-node attention halves ----------------
template<int H>
__global__ __launch_bounds__(256) void node_alpha(const float* __restrict__ h,
                                                  const float* __restrict__ att_s,
                                                  const float* __restrict__ att_d,
                                                  float* __restrict__ as_, float* __restrict__ ad_,
                                                  int N) {
    int w = (blockIdx.x * blockDim.x + threadIdx.x) >> 6;
    int lane = threadIdx.x & 63;
    if (w >= N) return;
#pragma unroll
    for (int hh = 0; hh < H; ++hh) {
        float v = h[(size_t)w * (H * 64) + hh * 64 + lane];
        float s = v * att_s[hh * 64 + lane];
        float d = v * att_d[hh * 64 + lane];
        s = wred_sum(s);
        d = wred_sum(d);
        if (lane == 0) {
            as_[(size_t)w * H + hh] = s;
            ad_[(size_t)w * H + hh] = d;
        }
    }
}

// ---------------- fused softmax + aggregation, one wave per dst ----------------
template<int H, int HC, bool DO_ELU>
__global__ __launch_bounds__(256) void gat_agg(const int* __restrict__ rowptr,
                                               const int* __restrict__ srcs,
                                               const float* __restrict__ as_,
                                               const float* __restrict__ ad_,
                                               const float* __restrict__ hfeat,
                                               const float* __restrict__ bias,
                                               float* __restrict__ outp, int N) {
    constexpr int P = HC / 64;
    int wid = threadIdx.x >> 6, lane = threadIdx.x & 63;
    int d = blockIdx.x * 4 + wid;
    if (d >= N) return;
    int r0 = rowptr[d], r1 = rowptr[d + 1];
    float uad[H];
#pragma unroll
    for (int h = 0; h < H; ++h) uad[h] = ad_[(size_t)d * H + h];
    float acc[P] = {};

    if (r1 - r0 <= 64) {
        // fast path: whole neighborhood fits one wave pass
        int i = r0 + lane;
        bool act = i < r1;
        int se = act ? srcs[i] : 0;
        float ax[H];
#pragma unroll
        for (int h = 0; h < H; ++h) {
            float sc = act ? lrelu(as_[(size_t)se * H + h] + uad[h]) : -3.4e38f;
            float m = wred_max(sc);
            float ex = act ? expf(sc - m) : 0.f;
            float den = wred_sum(ex);
            ax[h] = ex / (den + 1e-16f);
        }
        int cnt = r1 - r0;
        int t = 0;
        for (; t + 1 < cnt; t += 2) {
            int st0 = __shfl(se, t), st1 = __shfl(se, t + 1);
            float a0[H], a1[H];
#pragma unroll
            for (int h = 0; h < H; ++h) { a0[h] = __shfl(ax[h], t); a1[h] = __shfl(ax[h], t + 1); }
#pragma unroll
            for (int p = 0; p < P; ++p) {
                float v0 = hfeat[(size_t)st0 * HC + p * 64 + lane];
                float v1 = hfeat[(size_t)st1 * HC + p * 64 + lane];
                acc[p] += a0[p] * v0 + a1[p] * v1;
            }
        }
        for (; t < cnt; ++t) {
            int st = __shfl(se, t);
            float a[H];
#pragma unroll
            for (int h = 0; h < H; ++h) a[h] = __shfl(ax[h], t);
#pragma unroll
            for (int p = 0; p < P; ++p)
                acc[p] += a[p] * hfeat[(size_t)st * HC + p * 64 + lane];
        }
    } else {
        // generic chunked path
        float mx[H];
#pragma unroll
        for (int h = 0; h < H; ++h) mx[h] = -3.4e38f;
        for (int base = r0; base < r1; base += 64) {
            int i = base + lane;
            bool act = i < r1;
            int s = act ? srcs[i] : 0;
#pragma unroll
            for (int h = 0; h < H; ++h) {
                float sc = act ? lrelu(as_[(size_t)s * H + h] + uad[h]) : -3.4e38f;
                mx[h] = fmaxf(mx[h], sc);
            }
        }
#pragma unroll
        for (int h = 0; h < H; ++h) mx[h] = wred_max(mx[h]);
        float den[H] = {};
        for (int base = r0; base < r1; base += 64) {
            int i = base + lane;
            bool act = i < r1;
            int s = act ? srcs[i] : 0;
#pragma unroll
            for (int h = 0; h < H; ++h) {
                float ex = act ? expf(lrelu(as_[(size_t)s * H + h] + uad[h]) - mx[h]) : 0.f;
                den[h] += ex;
            }
        }
        float inv[H];
#pragma unroll
        for (int h = 0; h < H; ++h) inv[h] = 1.f / (wred_sum(den[h]) + 1e-16f);
        for (int base = r0; base < r1; base += 64) {
            int i = base + lane;
            bool act = i < r1;
            int s = act ? srcs[i] : 0;
            float ax[H];
#pragma unroll
            for (int h = 0; h < H; ++h)
                ax[h] = act ? expf(lrelu(as_[(size_t)s * H + h] + uad[h]) - mx[h]) * inv[h] : 0.f;
            int cnt = min(64, r1 - base);
            for (int t = 0; t < cnt; ++t) {
                int st = __shfl(s, t);
                float a[H];
#pragma unroll
                for (int h = 0; h < H; ++h) a[h] = __shfl(ax[h], t);
#pragma unroll
                for (int p = 0; p < P; ++p)
                    acc[p] += a[p] * hfeat[(size_t)st * HC + p * 64 + lane];
            }
        }
    }
#pragma unroll
    for (int p = 0; p < P; ++p) {
        float v = acc[p] + bias[p * 64 + lane];
        if (DO_ELU) v = v > 0.f ? v : expm1f(v);
        outp[(size_t)d * HC + p * 64 + lane] = v;
    }
}

extern "C" void kernel_launch(void* const* d_in, const int* in_sizes, int n_in,
                              void* d_out, int out_size, void* d_ws, size_t ws_size,
                              hipStream_t stream) {
    const float* x   = (const float*)d_in[0];
    const int*   ei  = (const int*)d_in[1];
    const float* W1  = (const float*)d_in[2];
    const float* a1s = (const float*)d_in[3];
    const float* a1d = (const float*)d_in[4];
    const float* b1  = (const float*)d_in[5];
    const float* W2  = (const float*)d_in[6];
    const float* a2s = (const float*)d_in[7];
    const float* a2d = (const float*)d_in[8];
    const float* b2  = (const float*)d_in[9];
    float* out = (float*)d_out;

    int N  = in_sizes[0] / 128;
    int E  = in_sizes[1] / 2;
    int Et = E + N;
    const int* src = ei;
    const int* dst = ei + E;

    float* h1   = (float*)d_ws;                       // N*128
    float* act1 = h1 + (size_t)N * 128;               // N*128
    float* as1  = act1 + (size_t)N * 128;             // 2N
    float* ad1  = as1 + (size_t)N * 2;                // 2N
    float* as2  = ad1 + (size_t)N * 2;                // N
    float* ad2  = as2 + N;                            // N
    int* rowptr = (int*)(ad2 + N);                    // N+1
    int* deg    = rowptr + N + 1;                     // N
    int* srcs   = deg + N;                            // Et
    float* h2   = h1;                                 // reuse after layer 1

    // ---- CSR build (graph shared by both layers) ----
    hipMemsetAsync(deg, 0, (size_t)N * 4, stream);
    count_deg<<<(Et + 255) / 256, 256, 0, stream>>>(dst, E, Et, deg);
    scan_deg<<<1, 256, 0, stream>>>(deg, rowptr, N);
    hipMemsetAsync(deg, 0, (size_t)N * 4, stream);
    scatter_edges<<<(Et + 255) / 256, 256, 0, stream>>>(src, dst, E, Et, rowptr, deg, srcs);

    // ---- layer 1 ----
    gemm_rt<128><<<(N + 31) / 32, 256, 0, stream>>>(x, W1, h1, N);
    node_alpha<2><<<(N + 3) / 4, 256, 0, stream>>>(h1, a1s, a1d, as1, ad1, N);
    gat_agg<2, 128, true><<<(N + 3) / 4, 256, 0, stream>>>(rowptr, srcs, as1, ad1, h1, b1, act1, N);

    // ---- layer 2 ----
    gemm_rt<64><<<(N + 31) / 32, 256, 0, stream>>>(act1, W2, h2, N);
    node_alpha<1><<<(N + 3) / 4, 256, 0, stream>>>(h2, a2s, a2d, as2, ad2, N);
    gat_agg<1, 64, false><<<(N + 3) / 4, 256, 0, stream>>>(rowptr, srcs, as2, ad2, h2, b2, out, N);
}

// Round 3
// 327.758 us; speedup vs baseline: 3.5878x; 1.4189x over previous
//
#include <hip/hip_runtime.h>
#include <hip/hip_bf16.h>
#include <math.h>

__device__ __forceinline__ float lrelu(float x) { return x > 0.f ? x : 0.2f * x; }
__device__ __forceinline__ float wred_max(float v) {
#pragma unroll
    for (int o = 32; o; o >>= 1) v = fmaxf(v, __shfl_xor(v, o));
    return v;
}
__device__ __forceinline__ float wred_sum(float v) {
#pragma unroll
    for (int o = 32; o; o >>= 1) v += __shfl_xor(v, o);
    return v;
}

// ---------------- CSR build ----------------
__global__ __launch_bounds__(256) void count_deg(const int* __restrict__ dst,
                                                 int E, int Et, int* __restrict__ deg) {
    int e = blockIdx.x * blockDim.x + threadIdx.x;
    if (e >= Et) return;
    int d = (e < E) ? dst[e] : (e - E);
    atomicAdd(&deg[d], 1);
}

// phase 1: per-256-chunk partial sums
__global__ __launch_bounds__(256) void scan_p1(const int* __restrict__ deg,
                                               int* __restrict__ partial, int N) {
    __shared__ int ws[4];
    int tid = threadIdx.x, lane = tid & 63, w = tid >> 6;
    int idx = blockIdx.x * 256 + tid;
    int v = (idx < N) ? deg[idx] : 0;
    int s = v;
#pragma unroll
    for (int o = 32; o; o >>= 1) s += __shfl_xor(s, o);
    if (lane == 0) ws[w] = s;
    __syncthreads();
    if (tid == 0) partial[blockIdx.x] = ws[0] + ws[1] + ws[2] + ws[3];
}

// phase 2: single-block exclusive scan of partials (nb <= a few thousand)
__global__ __launch_bounds__(256) void scan_p2(int* __restrict__ partial, int nb) {
    __shared__ int ws[4];
    __shared__ int s_carry;
    int tid = threadIdx.x, lane = tid & 63, w = tid >> 6;
    if (tid == 0) s_carry = 0;
    __syncthreads();
    for (int base = 0; base < nb; base += 256) {
        int idx = base + tid;
        int v = (idx < nb) ? partial[idx] : 0;
        int incl = v;
#pragma unroll
        for (int off = 1; off < 64; off <<= 1) {
            int t = __shfl_up(incl, off);
            if (lane >= off) incl += t;
        }
        if (lane == 63) ws[w] = incl;
        __syncthreads();
        int wpre = 0;
        for (int k = 0; k < w; ++k) wpre += ws[k];
        int carry = s_carry;
        if (idx < nb) partial[idx] = carry + wpre + incl - v;
        __syncthreads();
        if (tid == 255) s_carry = carry + wpre + incl;
        __syncthreads();
    }
}

// phase 3: local exclusive scan + chunk offset -> rowptr
__global__ __launch_bounds__(256) void scan_p3(const int* __restrict__ deg,
                                               const int* __restrict__ partial,
                                               int* __restrict__ rowptr, int N, int Et) {
    __shared__ int ws[4];
    int tid = threadIdx.x, lane = tid & 63, w = tid >> 6;
    int idx = blockIdx.x * 256 + tid;
    int v = (idx < N) ? deg[idx] : 0;
    int incl = v;
#pragma unroll
    for (int off = 1; off < 64; off <<= 1) {
        int t = __shfl_up(incl, off);
        if (lane >= off) incl += t;
    }
    if (lane == 63) ws[w] = incl;
    __syncthreads();
    int wpre = 0;
    for (int k = 0; k < w; ++k) wpre += ws[k];
    if (idx < N) rowptr[idx] = partial[blockIdx.x] + wpre + incl - v;
    if (idx == N - 1 || (blockIdx.x == gridDim.x - 1 && tid == 255))
        rowptr[N] = Et;
}

__global__ __launch_bounds__(256) void scatter_edges(const int* __restrict__ src,
                                                     const int* __restrict__ dst,
                                                     int E, int Et,
                                                     const int* __restrict__ rowptr,
                                                     int* __restrict__ cursor,
                                                     int* __restrict__ srcs) {
    int e = blockIdx.x * blockDim.x + threadIdx.x;
    if (e >= Et) return;
    int d = (e < E) ? dst[e] : (e - E);
    int s = (e < E) ? src[e] : (e - E);
    int pos = atomicAdd(&cursor[d], 1);
    srcs[rowptr[d] + pos] = s;
}

// ---------------- GEMM: C[N,M] = A[N,128] @ W[M,128]^T, reg-tiled ----------------
template<int M>
__global__ __launch_bounds__(256) void gemm_rt(const float* __restrict__ A,
                                               const float* __restrict__ W,
                                               float* __restrict__ C, int N) {
    constexpr int KB = 64;
    constexpr int LD = KB + 4;       // float row stride, 16B-aligned
    constexpr int CI = M / 32;       // cols per thread
    __shared__ float sA[32 * LD];
    __shared__ float sW[M * LD];
    int tid = threadIdx.x;
    int tx = tid & 31, ty = tid >> 5;
    int r0 = blockIdx.x * 32;
    float acc[4][CI] = {};
    for (int kt = 0; kt < 128; kt += KB) {
        for (int v = tid; v < 32 * (KB / 4); v += 256) {
            int rr = v / (KB / 4), kk = (v % (KB / 4)) * 4;
            float4 val = make_float4(0, 0, 0, 0);
            if (r0 + rr < N) val = *(const float4*)&A[(size_t)(r0 + rr) * 128 + kt + kk];
            *(float4*)&sA[rr * LD + kk] = val;
        }
        for (int v = tid; v < M * (KB / 4); v += 256) {
            int mr = v / (KB / 4), kk = (v % (KB / 4)) * 4;
            *(float4*)&sW[mr * LD + kk] = *(const float4*)&W[(size_t)mr * 128 + kt + kk];
        }
        __syncthreads();
#pragma unroll
        for (int k = 0; k < KB; k += 4) {
            float4 a4[4], w4[CI];
#pragma unroll
            for (int j = 0; j < 4; ++j) a4[j] = *(float4*)&sA[(ty + 8 * j) * LD + k];
#pragma unroll
            for (int i = 0; i < CI; ++i) w4[i] = *(float4*)&sW[(tx + 32 * i) * LD + k];
#pragma unroll
            for (int j = 0; j < 4; ++j)
#pragma unroll
                for (int i = 0; i < CI; ++i)
                    acc[j][i] += a4[j].x * w4[i].x + a4[j].y * w4[i].y +
                                 a4[j].z * w4[i].z + a4[j].w * w4[i].w;
        }
        __syncthreads();
    }
#pragma unroll
    for (int j = 0; j < 4; ++j) {
        int gr = r0 + ty + 8 * j;
        if (gr < N)
#pragma unroll
            for (int i = 0; i < CI; ++i)
                C[(size_t)gr * M + tx + 32 * i] = acc[j][i];
    }
}

// ---------------- per-node attention halves ----------------
template<int H>
__global__ __launch_bounds__(256) void node_alpha(const float* __restrict__ h,
                                                  const float* __restrict__ att_s,
                                                  const float* __restrict__ att_d,
                                                  float* __restrict__ as_, float* __restrict__ ad_,
                                                  int N) {
    int w = (blockIdx.x * blockDim.x + threadIdx.x) >> 6;
    int lane = threadIdx.x & 63;
    if (w >= N) return;
#pragma unroll
    for (int hh = 0; hh < H; ++hh) {
        float v = h[(size_t)w * (H * 64) + hh * 64 + lane];
        float s = v * att_s[hh * 64 + lane];
        float d = v * att_d[hh * 64 + lane];
        s = wred_sum(s);
        d = wred_sum(d);
        if (lane == 0) {
            as_[(size_t)w * H + hh] = s;
            ad_[(size_t)w * H + hh] = d;
        }
    }
}

// ---------------- fused softmax + aggregation, one wave per dst ----------------
template<int H, int HC, bool DO_ELU>
__global__ __launch_bounds__(256) void gat_agg(const int* __restrict__ rowptr,
                                               const int* __restrict__ srcs,
                                               const float* __restrict__ as_,
                                               const float* __restrict__ ad_,
                                               const float* __restrict__ hfeat,
                                               const float* __restrict__ bias,
                                               float* __restrict__ outp, int N) {
    constexpr int P = HC / 64;
    int wid = threadIdx.x >> 6, lane = threadIdx.x & 63;
    int d = blockIdx.x * 4 + wid;
    if (d >= N) return;
    int r0 = rowptr[d], r1 = rowptr[d + 1];
    float uad[H];
#pragma unroll
    for (int h = 0; h < H; ++h) uad[h] = ad_[(size_t)d * H + h];
    float acc[P] = {};

    if (r1 - r0 <= 64) {
        // fast path: whole neighborhood fits one wave pass
        int i = r0 + lane;
        bool act = i < r1;
        int se = act ? srcs[i] : 0;
        float ax[H];
#pragma unroll
        for (int h = 0; h < H; ++h) {
            float sc = act ? lrelu(as_[(size_t)se * H + h] + uad[h]) : -3.4e38f;
            float m = wred_max(sc);
            float ex = act ? expf(sc - m) : 0.f;
            float den = wred_sum(ex);
            ax[h] = ex / (den + 1e-16f);
        }
        int cnt = r1 - r0;
        int t = 0;
        for (; t + 1 < cnt; t += 2) {
            int st0 = __shfl(se, t), st1 = __shfl(se, t + 1);
            float a0[H], a1[H];
#pragma unroll
            for (int h = 0; h < H; ++h) { a0[h] = __shfl(ax[h], t); a1[h] = __shfl(ax[h], t + 1); }
#pragma unroll
            for (int p = 0; p < P; ++p) {
                float v0 = hfeat[(size_t)st0 * HC + p * 64 + lane];
                float v1 = hfeat[(size_t)st1 * HC + p * 64 + lane];
                acc[p] += a0[p] * v0 + a1[p] * v1;
            }
        }
        for (; t < cnt; ++t) {
            int st = __shfl(se, t);
            float a[H];
#pragma unroll
            for (int h = 0; h < H; ++h) a[h] = __shfl(ax[h], t);
#pragma unroll
            for (int p = 0; p < P; ++p)
                acc[p] += a[p] * hfeat[(size_t)st * HC + p * 64 + lane];
        }
    } else {
        // generic chunked path
        float mx[H];
#pragma unroll
        for (int h = 0; h < H; ++h) mx[h] = -3.4e38f;
        for (int base = r0; base < r1; base += 64) {
            int i = base + lane;
            bool act = i < r1;
            int s = act ? srcs[i] : 0;
#pragma unroll
            for (int h = 0; h < H; ++h) {
                float sc = act ? lrelu(as_[(size_t)s * H + h] + uad[h]) : -3.4e38f;
                mx[h] = fmaxf(mx[h], sc);
            }
        }
#pragma unroll
        for (int h = 0; h < H; ++h) mx[h] = wred_max(mx[h]);
        float den[H] = {};
        for (int base = r0; base < r1; base += 64) {
            int i = base + lane;
            bool act = i < r1;
            int s = act ? srcs[i] : 0;
#pragma unroll
            for (int h = 0; h < H; ++h) {
                float ex = act ? expf(lrelu(as_[(size_t)s * H + h] + uad[h]) - mx[h]) : 0.f;
                den[h] += ex;
            }
        }
        float inv[H];
#pragma unroll
        for (int h = 0; h < H; ++h) inv[h] = 1.f / (wred_sum(den[h]) + 1e-16f);
        for (int base = r0; base < r1; base += 64) {
            int i = base + lane;
            bool act = i < r1;
            int s = act ? srcs[i] : 0;
            float ax[H];
#pragma unroll
            for (int h = 0; h < H; ++h)
                ax[h] = act ? expf(lrelu(as_[(size_t)s * H + h] + uad[h]) - mx[h]) * inv[h] : 0.f;
            int cnt = min(64, r1 - base);
            for (int t = 0; t < cnt; ++t) {
                int st = __shfl(s, t);
                float a[H];
#pragma unroll
                for (int h = 0; h < H; ++h) a[h] = __shfl(ax[h], t);
#pragma unroll
                for (int p = 0; p < P; ++p)
                    acc[p] += a[p] * hfeat[(size_t)st * HC + p * 64 + lane];
            }
        }
    }
#pragma unroll
    for (int p = 0; p < P; ++p) {
        float v = acc[p] + bias[p * 64 + lane];
        if (DO_ELU) v = v > 0.f ? v : expm1f(v);
        outp[(size_t)d * HC + p * 64 + lane] = v;
    }
}

extern "C" void kernel_launch(void* const* d_in, const int* in_sizes, int n_in,
                              void* d_out, int out_size, void* d_ws, size_t ws_size,
                              hipStream_t stream) {
    const float* x   = (const float*)d_in[0];
    const int*   ei  = (const int*)d_in[1];
    const float* W1  = (const float*)d_in[2];
    const float* a1s = (const float*)d_in[3];
    const float* a1d = (const float*)d_in[4];
    const float* b1  = (const float*)d_in[5];
    const float* W2  = (const float*)d_in[6];
    const float* a2s = (const float*)d_in[7];
    const float* a2d = (const float*)d_in[8];
    const float* b2  = (const float*)d_in[9];
    float* out = (float*)d_out;

    int N  = in_sizes[0] / 128;
    int E  = in_sizes[1] / 2;
    int Et = E + N;
    const int* src = ei;
    const int* dst = ei + E;
    int nb = (N + 255) / 256;

    float* h1   = (float*)d_ws;                       // N*128
    float* act1 = h1 + (size_t)N * 128;               // N*128
    float* as1  = act1 + (size_t)N * 128;             // 2N
    float* ad1  = as1 + (size_t)N * 2;                // 2N
    float* as2  = ad1 + (size_t)N * 2;                // N
    float* ad2  = as2 + N;                            // N
    int* rowptr = (int*)(ad2 + N);                    // N+1
    int* deg    = rowptr + N + 1;                     // N
    int* partial= deg + N;                            // nb
    int* srcs   = partial + nb;                       // Et
    float* h2   = h1;                                 // reuse after layer 1

    // ---- CSR build (graph shared by both layers) ----
    hipMemsetAsync(deg, 0, (size_t)N * 4, stream);
    count_deg<<<(Et + 255) / 256, 256, 0, stream>>>(dst, E, Et, deg);
    scan_p1<<<nb, 256, 0, stream>>>(deg, partial, N);
    scan_p2<<<1, 256, 0, stream>>>(partial, nb);
    scan_p3<<<nb, 256, 0, stream>>>(deg, partial, rowptr, N, Et);
    hipMemsetAsync(deg, 0, (size_t)N * 4, stream);
    scatter_edges<<<(Et + 255) / 256, 256, 0, stream>>>(src, dst, E, Et, rowptr, deg, srcs);

    // ---- layer 1 ----
    gemm_rt<128><<<(N + 31) / 32, 256, 0, stream>>>(x, W1, h1, N);
    node_alpha<2><<<(N + 3) / 4, 256, 0, stream>>>(h1, a1s, a1d, as1, ad1, N);
    gat_agg<2, 128, true><<<(N + 3) / 4, 256, 0, stream>>>(rowptr, srcs, as1, ad1, h1, b1, act1, N);

    // ---- layer 2 ----
    gemm_rt<64><<<(N + 31) / 32, 256, 0, stream>>>(act1, W2, h2, N);
    node_alpha<1><<<(N + 3) / 4, 256, 0, stream>>>(h2, a2s, a2d, as2, ad2, N);
    gat_agg<1, 64, false><<<(N + 3) / 4, 256, 0, stream>>>(rowptr, srcs, as2, ad2, h2, b2, out, N);
}

// Round 4
// 249.777 us; speedup vs baseline: 4.7079x; 1.3122x over previous
//
#include <hip/hip_runtime.h>
#include <hip/hip_bf16.h>
#include <math.h>

typedef __bf16 bf16x8 __attribute__((ext_vector_type(8)));
typedef float f32x4 __attribute__((ext_vector_type(4)));

__device__ __forceinline__ float lrelu(float x) { return x > 0.f ? x : 0.2f * x; }
__device__ __forceinline__ unsigned short f2bf(float f) {
    unsigned u = __float_as_uint(f);
    return (unsigned short)((u + 0x7fffu + ((u >> 16) & 1u)) >> 16);
}
__device__ __forceinline__ float wred_max(float v) {
#pragma unroll
    for (int o = 32; o; o >>= 1) v = fmaxf(v, __shfl_xor(v, o));
    return v;
}
__device__ __forceinline__ float wred_sum(float v) {
#pragma unroll
    for (int o = 32; o; o >>= 1) v += __shfl_xor(v, o);
    return v;
}

// ---------------- f32 -> bf16 cast (n % 8 == 0) ----------------
__global__ __launch_bounds__(256) void cast_bf16(const float* __restrict__ in,
                                                 unsigned short* __restrict__ out, size_t n) {
    size_t i = ((size_t)blockIdx.x * 256 + threadIdx.x) * 8;
    if (i >= n) return;
    float4 v0 = *(const float4*)(in + i);
    float4 v1 = *(const float4*)(in + i + 4);
    union { unsigned short u[8]; uint4 q; } o;
    o.u[0] = f2bf(v0.x); o.u[1] = f2bf(v0.y); o.u[2] = f2bf(v0.z); o.u[3] = f2bf(v0.w);
    o.u[4] = f2bf(v1.x); o.u[5] = f2bf(v1.y); o.u[6] = f2bf(v1.z); o.u[7] = f2bf(v1.w);
    *(uint4*)(out + i) = o.q;
}

// ---------------- CSR build ----------------
__global__ __launch_bounds__(256) void count_deg(const int* __restrict__ dst,
                                                 int E, int Et, int* __restrict__ deg) {
    int e = blockIdx.x * blockDim.x + threadIdx.x;
    if (e >= Et) return;
    int d = (e < E) ? dst[e] : (e - E);
    atomicAdd(&deg[d], 1);
}

__global__ __launch_bounds__(256) void scan_p1(const int* __restrict__ deg,
                                               int* __restrict__ partial, int N) {
    __shared__ int ws[4];
    int tid = threadIdx.x, lane = tid & 63, w = tid >> 6;
    int idx = blockIdx.x * 256 + tid;
    int v = (idx < N) ? deg[idx] : 0;
    int s = v;
#pragma unroll
    for (int o = 32; o; o >>= 1) s += __shfl_xor(s, o);
    if (lane == 0) ws[w] = s;
    __syncthreads();
    if (tid == 0) partial[blockIdx.x] = ws[0] + ws[1] + ws[2] + ws[3];
}

__global__ __launch_bounds__(256) void scan_p2(int* __restrict__ partial, int nb) {
    __shared__ int ws[4];
    __shared__ int s_carry;
    int tid = threadIdx.x, lane = tid & 63, w = tid >> 6;
    if (tid == 0) s_carry = 0;
    __syncthreads();
    for (int base = 0; base < nb; base += 256) {
        int idx = base + tid;
        int v = (idx < nb) ? partial[idx] : 0;
        int incl = v;
#pragma unroll
        for (int off = 1; off < 64; off <<= 1) {
            int t = __shfl_up(incl, off);
            if (lane >= off) incl += t;
        }
        if (lane == 63) ws[w] = incl;
        __syncthreads();
        int wpre = 0;
        for (int k = 0; k < w; ++k) wpre += ws[k];
        int carry = s_carry;
        if (idx < nb) partial[idx] = carry + wpre + incl - v;
        __syncthreads();
        if (tid == 255) s_carry = carry + wpre + incl;
        __syncthreads();
    }
}

__global__ __launch_bounds__(256) void scan_p3(const int* __restrict__ deg,
                                               const int* __restrict__ partial,
                                               int* __restrict__ rowptr, int N, int Et) {
    __shared__ int ws[4];
    int tid = threadIdx.x, lane = tid & 63, w = tid >> 6;
    int idx = blockIdx.x * 256 + tid;
    int v = (idx < N) ? deg[idx] : 0;
    int incl = v;
#pragma unroll
    for (int off = 1; off < 64; off <<= 1) {
        int t = __shfl_up(incl, off);
        if (lane >= off) incl += t;
    }
    if (lane == 63) ws[w] = incl;
    __syncthreads();
    int wpre = 0;
    for (int k = 0; k < w; ++k) wpre += ws[k];
    if (idx < N) rowptr[idx] = partial[blockIdx.x] + wpre + incl - v;
    if (idx == N - 1) rowptr[N] = Et;
}

__global__ __launch_bounds__(256) void scatter_edges(const int* __restrict__ src,
                                                     const int* __restrict__ dst,
                                                     int E, int Et,
                                                     const int* __restrict__ rowptr,
                                                     int* __restrict__ cursor,
                                                     int* __restrict__ srcs) {
    int e = blockIdx.x * blockDim.x + threadIdx.x;
    if (e >= Et) return;
    int d = (e < E) ? dst[e] : (e - E);
    int s = (e < E) ? src[e] : (e - E);
    int pos = atomicAdd(&cursor[d], 1);
    srcs[rowptr[d] + pos] = s;
}

// ---------------- MFMA GEMM + fused node_alpha ----------------
// C[N,M] = A[N,128] @ W[M,128]^T ; as/ad[N,H] = rowwise dot with att vectors.
// Block = 4 waves, each wave: 32 rows x M cols. A,B frags loaded direct from global.
template<int M, int H>
__global__ __launch_bounds__(256) void gemm_mfma(const unsigned short* __restrict__ Ab,
                                                 const unsigned short* __restrict__ Wb,
                                                 const float* __restrict__ att_s,
                                                 const float* __restrict__ att_d,
                                                 float* __restrict__ C,
                                                 float* __restrict__ as_,
                                                 float* __restrict__ ad_,
                                                 int N) {
    constexpr int CT = M / 16;
    int tid = threadIdx.x;
    int wid = tid >> 6, l = tid & 63;
    int l15 = l & 15, lhi = l >> 4;
    int rowbase = blockIdx.x * 128 + wid * 32;
    f32x4 acc[2][CT] = {};

    int r0c = min(rowbase + l15, N - 1);
    int r1c = min(rowbase + 16 + l15, N - 1);
    const unsigned short* a0p = Ab + (size_t)r0c * 128 + lhi * 8;
    const unsigned short* a1p = Ab + (size_t)r1c * 128 + lhi * 8;
    const unsigned short* wp  = Wb + (size_t)l15 * 128 + lhi * 8;

#pragma unroll
    for (int ks = 0; ks < 4; ++ks) {
        int k0 = ks * 32;
        bf16x8 a0 = *reinterpret_cast<const bf16x8*>(a0p + k0);
        bf16x8 a1 = *reinterpret_cast<const bf16x8*>(a1p + k0);
#pragma unroll
        for (int ct = 0; ct < CT; ++ct) {
            bf16x8 b = *reinterpret_cast<const bf16x8*>(wp + (size_t)ct * 16 * 128 + k0);
            acc[0][ct] = __builtin_amdgcn_mfma_f32_16x16x32_bf16(a0, b, acc[0][ct], 0, 0, 0);
            acc[1][ct] = __builtin_amdgcn_mfma_f32_16x16x32_bf16(a1, b, acc[1][ct], 0, 0, 0);
        }
    }

#pragma unroll
    for (int rt = 0; rt < 2; ++rt) {
        int rbase = rowbase + rt * 16 + lhi * 4;
        // store C (f32)
#pragma unroll
        for (int j = 0; j < 4; ++j) {
            int gr = rbase + j;
            if (gr < N) {
#pragma unroll
                for (int ct = 0; ct < CT; ++ct)
                    C[(size_t)gr * M + ct * 16 + l15] = acc[rt][ct][j];
            }
        }
        // fused per-row attention halves
#pragma unroll
        for (int hd = 0; hd < H; ++hd) {
            float ps0 = 0.f, ps1 = 0.f, ps2 = 0.f, ps3 = 0.f;
            float pd0 = 0.f, pd1 = 0.f, pd2 = 0.f, pd3 = 0.f;
#pragma unroll
            for (int c4 = 0; c4 < 4; ++c4) {
                int ct = hd * 4 + c4;
                float ws = att_s[hd * 64 + c4 * 16 + l15];
                float wd = att_d[hd * 64 + c4 * 16 + l15];
                ps0 += acc[rt][ct][0] * ws; pd0 += acc[rt][ct][0] * wd;
                ps1 += acc[rt][ct][1] * ws; pd1 += acc[rt][ct][1] * wd;
                ps2 += acc[rt][ct][2] * ws; pd2 += acc[rt][ct][2] * wd;
                ps3 += acc[rt][ct][3] * ws; pd3 += acc[rt][ct][3] * wd;
            }
#pragma unroll
            for (int o = 1; o < 16; o <<= 1) {
                ps0 += __shfl_xor(ps0, o); pd0 += __shfl_xor(pd0, o);
                ps1 += __shfl_xor(ps1, o); pd1 += __shfl_xor(pd1, o);
                ps2 += __shfl_xor(ps2, o); pd2 += __shfl_xor(pd2, o);
                ps3 += __shfl_xor(ps3, o); pd3 += __shfl_xor(pd3, o);
            }
            if (l15 == 0) {
                int gr = rbase;
                if (gr < N)     { as_[(size_t)gr * H + hd] = ps0; ad_[(size_t)gr * H + hd] = pd0; }
                if (gr + 1 < N) { as_[(size_t)(gr + 1) * H + hd] = ps1; ad_[(size_t)(gr + 1) * H + hd] = pd1; }
                if (gr + 2 < N) { as_[(size_t)(gr + 2) * H + hd] = ps2; ad_[(size_t)(gr + 2) * H + hd] = pd2; }
                if (gr + 3 < N) { as_[(size_t)(gr + 3) * H + hd] = ps3; ad_[(size_t)(gr + 3) * H + hd] = pd3; }
            }
        }
    }
}

// ---------------- fused softmax + aggregation, one wave per dst ----------------
template<int H, int HC, bool DO_ELU, bool OUTBF>
__global__ __launch_bounds__(256) void gat_agg(const int* __restrict__ rowptr,
                                               const int* __restrict__ srcs,
                                               const float* __restrict__ as_,
                                               const float* __restrict__ ad_,
                                               const float* __restrict__ hfeat,
                                               const float* __restrict__ bias,
                                               void* __restrict__ outp, int N) {
    constexpr int P = HC / 64;
    int wid = threadIdx.x >> 6, lane = threadIdx.x & 63;
    int d = blockIdx.x * 4 + wid;
    if (d >= N) return;
    int r0 = rowptr[d], r1 = rowptr[d + 1];
    float uad[H];
#pragma unroll
    for (int h = 0; h < H; ++h) uad[h] = ad_[(size_t)d * H + h];
    float acc[P] = {};

    if (r1 - r0 <= 64) {
        int i = r0 + lane;
        bool act = i < r1;
        int se = act ? srcs[i] : 0;
        float ax[H];
#pragma unroll
        for (int h = 0; h < H; ++h) {
            float sc = act ? lrelu(as_[(size_t)se * H + h] + uad[h]) : -3.4e38f;
            float m = wred_max(sc);
            float ex = act ? expf(sc - m) : 0.f;
            float den = wred_sum(ex);
            ax[h] = ex / (den + 1e-16f);
        }
        int cnt = r1 - r0;
        int t = 0;
        for (; t + 1 < cnt; t += 2) {
            int st0 = __shfl(se, t), st1 = __shfl(se, t + 1);
            float a0[H], a1[H];
#pragma unroll
            for (int h = 0; h < H; ++h) { a0[h] = __shfl(ax[h], t); a1[h] = __shfl(ax[h], t + 1); }
#pragma unroll
            for (int p = 0; p < P; ++p) {
                float v0 = hfeat[(size_t)st0 * HC + p * 64 + lane];
                float v1 = hfeat[(size_t)st1 * HC + p * 64 + lane];
                acc[p] += a0[p] * v0 + a1[p] * v1;
            }
        }
        for (; t < cnt; ++t) {
            int st = __shfl(se, t);
            float a[H];
#pragma unroll
            for (int h = 0; h < H; ++h) a[h] = __shfl(ax[h], t);
#pragma unroll
            for (int p = 0; p < P; ++p)
                acc[p] += a[p] * hfeat[(size_t)st * HC + p * 64 + lane];
        }
    } else {
        float mx[H];
#pragma unroll
        for (int h = 0; h < H; ++h) mx[h] = -3.4e38f;
        for (int base = r0; base < r1; base += 64) {
            int i = base + lane;
            bool act = i < r1;
            int s = act ? srcs[i] : 0;
#pragma unroll
            for (int h = 0; h < H; ++h) {
                float sc = act ? lrelu(as_[(size_t)s * H + h] + uad[h]) : -3.4e38f;
                mx[h] = fmaxf(mx[h], sc);
            }
        }
#pragma unroll
        for (int h = 0; h < H; ++h) mx[h] = wred_max(mx[h]);
        float den[H] = {};
        for (int base = r0; base < r1; base += 64) {
            int i = base + lane;
            bool act = i < r1;
            int s = act ? srcs[i] : 0;
#pragma unroll
            for (int h = 0; h < H; ++h) {
                float ex = act ? expf(lrelu(as_[(size_t)s * H + h] + uad[h]) - mx[h]) : 0.f;
                den[h] += ex;
            }
        }
        float inv[H];
#pragma unroll
        for (int h = 0; h < H; ++h) inv[h] = 1.f / (wred_sum(den[h]) + 1e-16f);
        for (int base = r0; base < r1; base += 64) {
            int i = base + lane;
            bool act = i < r1;
            int s = act ? srcs[i] : 0;
            float ax[H];
#pragma unroll
            for (int h = 0; h < H; ++h)
                ax[h] = act ? expf(lrelu(as_[(size_t)s * H + h] + uad[h]) - mx[h]) * inv[h] : 0.f;
            int cnt = min(64, r1 - base);
            for (int t = 0; t < cnt; ++t) {
                int st = __shfl(s, t);
                float a[H];
#pragma unroll
                for (int h = 0; h < H; ++h) a[h] = __shfl(ax[h], t);
#pragma unroll
                for (int p = 0; p < P; ++p)
                    acc[p] += a[p] * hfeat[(size_t)st * HC + p * 64 + lane];
            }
        }
    }
#pragma unroll
    for (int p = 0; p < P; ++p) {
        float v = acc[p] + bias[p * 64 + lane];
        if (DO_ELU) v = v > 0.f ? v : expm1f(v);
        if (OUTBF) ((unsigned short*)outp)[(size_t)d * HC + p * 64 + lane] = f2bf(v);
        else       ((float*)outp)[(size_t)d * HC + p * 64 + lane] = v;
    }
}

extern "C" void kernel_launch(void* const* d_in, const int* in_sizes, int n_in,
                              void* d_out, int out_size, void* d_ws, size_t ws_size,
                              hipStream_t stream) {
    const float* x   = (const float*)d_in[0];
    const int*   ei  = (const int*)d_in[1];
    const float* W1  = (const float*)d_in[2];
    const float* a1s = (const float*)d_in[3];
    const float* a1d = (const float*)d_in[4];
    const float* b1  = (const float*)d_in[5];
    const float* W2  = (const float*)d_in[6];
    const float* a2s = (const float*)d_in[7];
    const float* a2d = (const float*)d_in[8];
    const float* b2  = (const float*)d_in[9];
    float* out = (float*)d_out;

    int N  = in_sizes[0] / 128;
    int E  = in_sizes[1] / 2;
    int Et = E + N;
    const int* src = ei;
    const int* dst = ei + E;
    int nb = (N + 255) / 256;

    char* p = (char*)d_ws;
    float* h1 = (float*)p;                 p += (size_t)N * 128 * 4;
    unsigned short* xb = (unsigned short*)p;    p += (size_t)N * 128 * 2;
    unsigned short* act1b = (unsigned short*)p; p += (size_t)N * 128 * 2;
    unsigned short* w1b = (unsigned short*)p;   p += 128 * 128 * 2;
    unsigned short* w2b = (unsigned short*)p;   p += 64 * 128 * 2;
    float* as1 = (float*)p;                p += (size_t)N * 2 * 4;
    float* ad1 = (float*)p;                p += (size_t)N * 2 * 4;
    float* as2 = (float*)p;                p += (size_t)N * 4;
    float* ad2 = (float*)p;                p += (size_t)N * 4;
    int* rowptr = (int*)p;                 p += (size_t)(N + 1) * 4;
    int* deg = (int*)p;                    p += (size_t)N * 4;
    int* partial = (int*)p;                p += (size_t)nb * 4;
    int* srcs = (int*)p;                   p += (size_t)Et * 4;
    float* h2 = (float*)xb;                // alias: xb dead after gemm1

    // ---- CSR build ----
    hipMemsetAsync(deg, 0, (size_t)N * 4, stream);
    count_deg<<<(Et + 255) / 256, 256, 0, stream>>>(dst, E, Et, deg);
    scan_p1<<<nb, 256, 0, stream>>>(deg, partial, N);
    scan_p2<<<1, 256, 0, stream>>>(partial, nb);
    scan_p3<<<nb, 256, 0, stream>>>(deg, partial, rowptr, N, Et);
    hipMemsetAsync(deg, 0, (size_t)N * 4, stream);
    scatter_edges<<<(Et + 255) / 256, 256, 0, stream>>>(src, dst, E, Et, rowptr, deg, srcs);

    // ---- casts ----
    cast_bf16<<<((size_t)N * 128 / 8 + 255) / 256, 256, 0, stream>>>(x, xb, (size_t)N * 128);
    cast_bf16<<<(128 * 128 / 8 + 255) / 256, 256, 0, stream>>>(W1, w1b, 128 * 128);
    cast_bf16<<<(64 * 128 / 8 + 255) / 256, 256, 0, stream>>>(W2, w2b, 64 * 128);

    // ---- layer 1 ----
    gemm_mfma<128, 2><<<(N + 127) / 128, 256, 0, stream>>>(xb, w1b, a1s, a1d, h1, as1, ad1, N);
    gat_agg<2, 128, true, true><<<(N + 3) / 4, 256, 0, stream>>>(rowptr, srcs, as1, ad1, h1, b1, act1b, N);

    // ---- layer 2 ----
    gemm_mfma<64, 1><<<(N + 127) / 128, 256, 0, stream>>>(act1b, w2b, a2s, a2d, h2, as2, ad2, N);
    gat_agg<1, 64, false, false><<<(N + 3) / 4, 256, 0, stream>>>(rowptr, srcs, as2, ad2, h2, b2, out, N);
}

// Round 6
// 233.782 us; speedup vs baseline: 5.0300x; 1.0684x over previous
//
#include <hip/hip_runtime.h>
#include <hip/hip_bf16.h>
#include <math.h>

typedef __bf16 bf16x8 __attribute__((ext_vector_type(8)));
typedef float f32x4 __attribute__((ext_vector_type(4)));
typedef __fp16 fp16x2 __attribute__((ext_vector_type(2)));

__device__ __forceinline__ float lrelu(float x) { return x > 0.f ? x : 0.2f * x; }
__device__ __forceinline__ unsigned short f2bf(float f) {
    unsigned u = __float_as_uint(f);
    return (unsigned short)((u + 0x7fffu + ((u >> 16) & 1u)) >> 16);
}
__device__ __forceinline__ float bf16lo(unsigned u) { return __uint_as_float(u << 16); }
__device__ __forceinline__ float bf16hi(unsigned u) { return __uint_as_float(u & 0xffff0000u); }
__device__ __forceinline__ unsigned pkf16(float a, float b) {
    union { fp16x2 h; unsigned u; } c;
    c.h = __builtin_amdgcn_cvt_pkrtz(a, b);
    return c.u;
}
__device__ __forceinline__ float f16b2f(unsigned short b) {
    union { unsigned short u; __fp16 h; } c; c.u = b; return (float)c.h;
}
__device__ __forceinline__ float wred_max(float v) {
#pragma unroll
    for (int o = 32; o; o >>= 1) v = fmaxf(v, __shfl_xor(v, o));
    return v;
}
__device__ __forceinline__ float wred_sum(float v) {
#pragma unroll
    for (int o = 32; o; o >>= 1) v += __shfl_xor(v, o);
    return v;
}

// ---------------- f32 -> bf16 cast (n % 8 == 0) ----------------
__global__ __launch_bounds__(256) void cast_bf16(const float* __restrict__ in,
                                                 unsigned short* __restrict__ out, size_t n) {
    size_t i = ((size_t)blockIdx.x * 256 + threadIdx.x) * 8;
    if (i >= n) return;
    float4 v0 = *(const float4*)(in + i);
    float4 v1 = *(const float4*)(in + i + 4);
    union { unsigned short u[8]; uint4 q; } o;
    o.u[0] = f2bf(v0.x); o.u[1] = f2bf(v0.y); o.u[2] = f2bf(v0.z); o.u[3] = f2bf(v0.w);
    o.u[4] = f2bf(v1.x); o.u[5] = f2bf(v1.y); o.u[6] = f2bf(v1.z); o.u[7] = f2bf(v1.w);
    *(uint4*)(out + i) = o.q;
}

// ---------------- CSR build ----------------
__global__ __launch_bounds__(256) void count_deg(const int* __restrict__ dst,
                                                 int E, int Et, int* __restrict__ deg) {
    int e = blockIdx.x * blockDim.x + threadIdx.x;
    if (e >= Et) return;
    int d = (e < E) ? dst[e] : (e - E);
    atomicAdd(&deg[d], 1);
}

__global__ __launch_bounds__(256) void scan_p1(const int* __restrict__ deg,
                                               int* __restrict__ partial, int N) {
    __shared__ int ws[4];
    int tid = threadIdx.x, lane = tid & 63, w = tid >> 6;
    int idx = blockIdx.x * 256 + tid;
    int v = (idx < N) ? deg[idx] : 0;
    int s = v;
#pragma unroll
    for (int o = 32; o; o >>= 1) s += __shfl_xor(s, o);
    if (lane == 0) ws[w] = s;
    __syncthreads();
    if (tid == 0) partial[blockIdx.x] = ws[0] + ws[1] + ws[2] + ws[3];
}

__global__ __launch_bounds__(256) void scan_p2(int* __restrict__ partial, int nb) {
    __shared__ int ws[4];
    __shared__ int s_carry;
    int tid = threadIdx.x, lane = tid & 63, w = tid >> 6;
    if (tid == 0) s_carry = 0;
    __syncthreads();
    for (int base = 0; base < nb; base += 256) {
        int idx = base + tid;
        int v = (idx < nb) ? partial[idx] : 0;
        int incl = v;
#pragma unroll
        for (int off = 1; off < 64; off <<= 1) {
            int t = __shfl_up(incl, off);
            if (lane >= off) incl += t;
        }
        if (lane == 63) ws[w] = incl;
        __syncthreads();
        int wpre = 0;
        for (int k = 0; k < w; ++k) wpre += ws[k];
        int carry = s_carry;
        if (idx < nb) partial[idx] = carry + wpre + incl - v;
        __syncthreads();
        if (tid == 255) s_carry = carry + wpre + incl;
        __syncthreads();
    }
}

__global__ __launch_bounds__(256) void scan_p3(const int* __restrict__ deg,
                                               const int* __restrict__ partial,
                                               int* __restrict__ rowptr, int N, int Et) {
    __shared__ int ws[4];
    int tid = threadIdx.x, lane = tid & 63, w = tid >> 6;
    int idx = blockIdx.x * 256 + tid;
    int v = (idx < N) ? deg[idx] : 0;
    int incl = v;
#pragma unroll
    for (int off = 1; off < 64; off <<= 1) {
        int t = __shfl_up(incl, off);
        if (lane >= off) incl += t;
    }
    if (lane == 63) ws[w] = incl;
    __syncthreads();
    int wpre = 0;
    for (int k = 0; k < w; ++k) wpre += ws[k];
    if (idx < N) rowptr[idx] = partial[blockIdx.x] + wpre + incl - v;
    if (idx == N - 1) rowptr[N] = Et;
}

__global__ __launch_bounds__(256) void scatter_edges(const int* __restrict__ src,
                                                     const int* __restrict__ dst,
                                                     int E, int Et,
                                                     const int* __restrict__ rowptr,
                                                     int* __restrict__ cursor,
                                                     int* __restrict__ srcs) {
    int e = blockIdx.x * blockDim.x + threadIdx.x;
    if (e >= Et) return;
    int d = (e < E) ? dst[e] : (e - E);
    int s = (e < E) ? src[e] : (e - E);
    int pos = atomicAdd(&cursor[d], 1);
    srcs[rowptr[d] + pos] = s;
}

// ---------------- MFMA GEMM (bf16 out) + fused node_alpha ----------------
template<int M, int H>
__global__ __launch_bounds__(256) void gemm_mfma(const unsigned short* __restrict__ Ab,
                                                 const unsigned short* __restrict__ Wb,
                                                 const float* __restrict__ att_s,
                                                 const float* __restrict__ att_d,
                                                 unsigned short* __restrict__ Cb,
                                                 float* __restrict__ as_,
                                                 float* __restrict__ ad_,
                                                 int N) {
    constexpr int CT = M / 16;
    int tid = threadIdx.x;
    int wid = tid >> 6, l = tid & 63;
    int l15 = l & 15, lhi = l >> 4;
    int rowbase = blockIdx.x * 128 + wid * 32;
    f32x4 acc[2][CT] = {};

    int r0c = min(rowbase + l15, N - 1);
    int r1c = min(rowbase + 16 + l15, N - 1);
    const unsigned short* a0p = Ab + (size_t)r0c * 128 + lhi * 8;
    const unsigned short* a1p = Ab + (size_t)r1c * 128 + lhi * 8;
    const unsigned short* wp  = Wb + (size_t)l15 * 128 + lhi * 8;

#pragma unroll
    for (int ks = 0; ks < 4; ++ks) {
        int k0 = ks * 32;
        bf16x8 a0 = *reinterpret_cast<const bf16x8*>(a0p + k0);
        bf16x8 a1 = *reinterpret_cast<const bf16x8*>(a1p + k0);
#pragma unroll
        for (int ct = 0; ct < CT; ++ct) {
            bf16x8 b = *reinterpret_cast<const bf16x8*>(wp + (size_t)ct * 16 * 128 + k0);
            acc[0][ct] = __builtin_amdgcn_mfma_f32_16x16x32_bf16(a0, b, acc[0][ct], 0, 0, 0);
            acc[1][ct] = __builtin_amdgcn_mfma_f32_16x16x32_bf16(a1, b, acc[1][ct], 0, 0, 0);
        }
    }

#pragma unroll
    for (int rt = 0; rt < 2; ++rt) {
        int rbase = rowbase + rt * 16 + lhi * 4;
#pragma unroll
        for (int j = 0; j < 4; ++j) {
            int gr = rbase + j;
            if (gr < N) {
#pragma unroll
                for (int ct = 0; ct < CT; ++ct)
                    Cb[(size_t)gr * M + ct * 16 + l15] = f2bf(acc[rt][ct][j]);
            }
        }
#pragma unroll
        for (int hd = 0; hd < H; ++hd) {
            float ps0 = 0.f, ps1 = 0.f, ps2 = 0.f, ps3 = 0.f;
            float pd0 = 0.f, pd1 = 0.f, pd2 = 0.f, pd3 = 0.f;
#pragma unroll
            for (int c4 = 0; c4 < 4; ++c4) {
                int ct = hd * 4 + c4;
                float ws = att_s[hd * 64 + c4 * 16 + l15];
                float wd = att_d[hd * 64 + c4 * 16 + l15];
                ps0 += acc[rt][ct][0] * ws; pd0 += acc[rt][ct][0] * wd;
                ps1 += acc[rt][ct][1] * ws; pd1 += acc[rt][ct][1] * wd;
                ps2 += acc[rt][ct][2] * ws; pd2 += acc[rt][ct][2] * wd;
                ps3 += acc[rt][ct][3] * ws; pd3 += acc[rt][ct][3] * wd;
            }
#pragma unroll
            for (int o = 1; o < 16; o <<= 1) {
                ps0 += __shfl_xor(ps0, o); pd0 += __shfl_xor(pd0, o);
                ps1 += __shfl_xor(ps1, o); pd1 += __shfl_xor(pd1, o);
                ps2 += __shfl_xor(ps2, o); pd2 += __shfl_xor(pd2, o);
                ps3 += __shfl_xor(ps3, o); pd3 += __shfl_xor(pd3, o);
            }
            if (l15 == 0) {
                int gr = rbase;
                if (gr < N)     { as_[(size_t)gr * H + hd] = ps0; ad_[(size_t)gr * H + hd] = pd0; }
                if (gr + 1 < N) { as_[(size_t)(gr + 1) * H + hd] = ps1; ad_[(size_t)(gr + 1) * H + hd] = pd1; }
                if (gr + 2 < N) { as_[(size_t)(gr + 2) * H + hd] = ps2; ad_[(size_t)(gr + 2) * H + hd] = pd2; }
                if (gr + 3 < N) { as_[(size_t)(gr + 3) * H + hd] = ps3; ad_[(size_t)(gr + 3) * H + hd] = pd3; }
            }
        }
    }
}

// ---------------- fused softmax + aggregation (bf16 features) ----------------
// H=2: HC=128, lane covers ch {2*il, 2*il+1}, head = lane>>5, bf16 out.
// H=1: HC=64,  2 edges/iter (32-lane groups), f32 out.
template<int H, bool DO_ELU>
__global__ __launch_bounds__(256) void gat_agg(const int* __restrict__ rowptr,
                                               const int* __restrict__ srcs,
                                               const float* __restrict__ as_,
                                               const float* __restrict__ ad_,
                                               const unsigned* __restrict__ hfeat,
                                               const float* __restrict__ bias,
                                               void* __restrict__ outp, int N) {
    constexpr int RW = 32 * H;   // u32 words per feature row
    int wid = threadIdx.x >> 6, lane = threadIdx.x & 63;
    int il = lane & (RW - 1);
    int grp = lane >> 5;
    int d = blockIdx.x * 4 + wid;
    if (d >= N) return;
    int r0 = rowptr[d], r1 = rowptr[d + 1];
    int cnt = r1 - r0;
    float uad[H];
#pragma unroll
    for (int h = 0; h < H; ++h) uad[h] = ad_[(size_t)d * H + h];
    float acc0 = 0.f, acc1 = 0.f;

    if (cnt <= 64) {
        int i = r0 + lane;
        bool act = i < r1;
        int se = act ? srcs[i] : 0;
        float ax[H];
#pragma unroll
        for (int h = 0; h < H; ++h) {
            float sc = act ? lrelu(as_[(size_t)se * H + h] + uad[h]) : -3.4e38f;
            float m = wred_max(sc);
            float ex = act ? expf(sc - m) : 0.f;
            float den = wred_sum(ex);
            ax[h] = ex / (den + 1e-16f);
        }
        if (H == 2) {
            unsigned apk = pkf16(ax[0], ax[H - 1]);
            int t = 0;
            for (; t + 1 < cnt; t += 2) {
                int st0 = __shfl(se, t), st1 = __shfl(se, t + 1);
                unsigned au0 = __shfl(apk, t), au1 = __shfl(apk, t + 1);
                float af0 = f16b2f((unsigned short)((lane < 32) ? (au0 & 0xffff) : (au0 >> 16)));
                float af1 = f16b2f((unsigned short)((lane < 32) ? (au1 & 0xffff) : (au1 >> 16)));
                unsigned u0 = hfeat[(size_t)st0 * RW + il];
                unsigned u1 = hfeat[(size_t)st1 * RW + il];
                acc0 += af0 * bf16lo(u0) + af1 * bf16lo(u1);
                acc1 += af0 * bf16hi(u0) + af1 * bf16hi(u1);
            }
            if (t < cnt) {
                int st = __shfl(se, t);
                unsigned au = __shfl(apk, t);
                float af = f16b2f((unsigned short)((lane < 32) ? (au & 0xffff) : (au >> 16)));
                unsigned u = hfeat[(size_t)st * RW + il];
                acc0 += af * bf16lo(u);
                acc1 += af * bf16hi(u);
            }
        } else {
            float afl = ax[0];
            for (int t = 0; t < cnt; t += 2) {
                int tt = t + grp;
                int st = __shfl(se, tt);
                float af = __shfl(afl, tt);
                if (tt >= cnt) af = 0.f;
                unsigned u = hfeat[(size_t)st * RW + il];
                acc0 += af * bf16lo(u);
                acc1 += af * bf16hi(u);
            }
        }
    } else {
        // generic chunked path (deg > 64) -- rare
        float mx[H];
#pragma unroll
        for (int h = 0; h < H; ++h) mx[h] = -3.4e38f;
        for (int base = r0; base < r1; base += 64) {
            int i = base + lane;
            bool act = i < r1;
            int s = act ? srcs[i] : 0;
#pragma unroll
            for (int h = 0; h < H; ++h) {
                float sc = act ? lrelu(as_[(size_t)s * H + h] + uad[h]) : -3.4e38f;
                mx[h] = fmaxf(mx[h], sc);
            }
        }
#pragma unroll
        for (int h = 0; h < H; ++h) mx[h] = wred_max(mx[h]);
        float den[H] = {};
        for (int base = r0; base < r1; base += 64) {
            int i = base + lane;
            bool act = i < r1;
            int s = act ? srcs[i] : 0;
#pragma unroll
            for (int h = 0; h < H; ++h)
                den[h] += act ? expf(lrelu(as_[(size_t)s * H + h] + uad[h]) - mx[h]) : 0.f;
        }
        float inv[H];
#pragma unroll
        for (int h = 0; h < H; ++h) inv[h] = 1.f / (wred_sum(den[h]) + 1e-16f);
        for (int base = r0; base < r1; base += 64) {
            int i = base + lane;
            bool act = i < r1;
            int se = act ? srcs[i] : 0;
            float ax[H];
#pragma unroll
            for (int h = 0; h < H; ++h)
                ax[h] = act ? expf(lrelu(as_[(size_t)se * H + h] + uad[h]) - mx[h]) * inv[h] : 0.f;
            int cntc = min(64, r1 - base);
            if (H == 2) {
                unsigned apk = pkf16(ax[0], ax[H - 1]);
                for (int t = 0; t < cntc; ++t) {
                    int st = __shfl(se, t);
                    unsigned au = __shfl(apk, t);
                    float af = f16b2f((unsigned short)((lane < 32) ? (au & 0xffff) : (au >> 16)));
                    unsigned u = hfeat[(size_t)st * RW + il];
                    acc0 += af * bf16lo(u);
                    acc1 += af * bf16hi(u);
                }
            } else {
                float afl = ax[0];
                for (int t = 0; t < cntc; t += 2) {
                    int tt = t + grp;
                    int sti = __shfl(se, tt);
                    float af = __shfl(afl, tt);
                    if (tt >= cntc) af = 0.f;
                    unsigned u = hfeat[(size_t)sti * RW + il];
                    acc0 += af * bf16lo(u);
                    acc1 += af * bf16hi(u);
                }
            }
        }
    }

    if (H == 1) {
        acc0 += __shfl_xor(acc0, 32);
        acc1 += __shfl_xor(acc1, 32);
        if (grp == 0) {
            float2 o;
            o.x = acc0 + bias[2 * il];
            o.y = acc1 + bias[2 * il + 1];
            if (DO_ELU) {
                o.x = o.x > 0.f ? o.x : expm1f(o.x);
                o.y = o.y > 0.f ? o.y : expm1f(o.y);
            }
            ((float2*)outp)[(size_t)d * RW + il] = o;
        }
    } else {
        float v0 = acc0 + bias[2 * il];
        float v1 = acc1 + bias[2 * il + 1];
        if (DO_ELU) {
            v0 = v0 > 0.f ? v0 : expm1f(v0);
            v1 = v1 > 0.f ? v1 : expm1f(v1);
        }
        unsigned o = (unsigned)f2bf(v0) | ((unsigned)f2bf(v1) << 16);
        ((unsigned*)outp)[(size_t)d * RW + il] = o;
    }
}

extern "C" void kernel_launch(void* const* d_in, const int* in_sizes, int n_in,
                              void* d_out, int out_size, void* d_ws, size_t ws_size,
                              hipStream_t stream) {
    const float* x   = (const float*)d_in[0];
    const int*   ei  = (const int*)d_in[1];
    const float* W1  = (const float*)d_in[2];
    const float* a1s = (const float*)d_in[3];
    const float* a1d = (const float*)d_in[4];
    const float* b1  = (const float*)d_in[5];
    const float* W2  = (const float*)d_in[6];
    const float* a2s = (const float*)d_in[7];
    const float* a2d = (const float*)d_in[8];
    const float* b2  = (const float*)d_in[9];
    float* out = (float*)d_out;

    int N  = in_sizes[0] / 128;
    int E  = in_sizes[1] / 2;
    int Et = E + N;
    const int* src = ei;
    const int* dst = ei + E;
    int nb = (N + 255) / 256;

    char* p = (char*)d_ws;
    unsigned short* xb = (unsigned short*)p;    p += (size_t)N * 128 * 2;
    unsigned short* h1b = (unsigned short*)p;   p += (size_t)N * 128 * 2;
    unsigned short* act1b = (unsigned short*)p; p += (size_t)N * 128 * 2;
    unsigned short* w1b = (unsigned short*)p;   p += 128 * 128 * 2;
    unsigned short* w2b = (unsigned short*)p;   p += 64 * 128 * 2;
    float* as1 = (float*)p;                p += (size_t)N * 2 * 4;
    float* ad1 = (float*)p;                p += (size_t)N * 2 * 4;
    float* as2 = (float*)p;                p += (size_t)N * 4;
    float* ad2 = (float*)p;                p += (size_t)N * 4;
    int* rowptr = (int*)p;                 p += (size_t)(N + 1) * 4;
    int* deg = (int*)p;                    p += (size_t)N * 4;
    int* partial = (int*)p;                p += (size_t)nb * 4;
    int* srcs = (int*)p;                   p += (size_t)Et * 4;
    unsigned short* h2b = xb;              // alias: xb dead after gemm1

    // ---- CSR build ----
    hipMemsetAsync(deg, 0, (size_t)N * 4, stream);
    count_deg<<<(Et + 255) / 256, 256, 0, stream>>>(dst, E, Et, deg);
    scan_p1<<<nb, 256, 0, stream>>>(deg, partial, N);
    scan_p2<<<1, 256, 0, stream>>>(partial, nb);
    scan_p3<<<nb, 256, 0, stream>>>(deg, partial, rowptr, N, Et);
    hipMemsetAsync(deg, 0, (size_t)N * 4, stream);
    scatter_edges<<<(Et + 255) / 256, 256, 0, stream>>>(src, dst, E, Et, rowptr, deg, srcs);

    // ---- casts ----
    cast_bf16<<<((size_t)N * 128 / 8 + 255) / 256, 256, 0, stream>>>(x, xb, (size_t)N * 128);
    cast_bf16<<<(128 * 128 / 8 + 255) / 256, 256, 0, stream>>>(W1, w1b, 128 * 128);
    cast_bf16<<<(64 * 128 / 8 + 255) / 256, 256, 0, stream>>>(W2, w2b, 64 * 128);

    // ---- layer 1 ----
    gemm_mfma<128, 2><<<(N + 127) / 128, 256, 0, stream>>>(xb, w1b, a1s, a1d, h1b, as1, ad1, N);
    gat_agg<2, true><<<(N + 3) / 4, 256, 0, stream>>>(rowptr, srcs, as1, ad1,
                                                      (const unsigned*)h1b, b1, act1b, N);

    // ---- layer 2 ----
    gemm_mfma<64, 1><<<(N + 127) / 128, 256, 0, stream>>>(act1b, w2b, a2s, a2d, h2b, as2, ad2, N);
    gat_agg<1, false><<<(N + 3) / 4, 256, 0, stream>>>(rowptr, srcs, as2, ad2,
                                                       (const unsigned*)h2b, b2, out, N);
}

// Round 7
// 226.502 us; speedup vs baseline: 5.1917x; 1.0321x over previous
//
#include <hip/hip_runtime.h>
#include <hip/hip_bf16.h>
#include <math.h>

typedef __bf16 bf16x8 __attribute__((ext_vector_type(8)));
typedef float f32x4 __attribute__((ext_vector_type(4)));
typedef __fp16 fp16x2 __attribute__((ext_vector_type(2)));

__device__ __forceinline__ float lrelu(float x) { return x > 0.f ? x : 0.2f * x; }
__device__ __forceinline__ unsigned short f2bf(float f) {
    unsigned u = __float_as_uint(f);
    return (unsigned short)((u + 0x7fffu + ((u >> 16) & 1u)) >> 16);
}
__device__ __forceinline__ float bf16lo(unsigned u) { return __uint_as_float(u << 16); }
__device__ __forceinline__ float bf16hi(unsigned u) { return __uint_as_float(u & 0xffff0000u); }
__device__ __forceinline__ unsigned pkf16(float a, float b) {
    union { fp16x2 h; unsigned u; } c;
    c.h = __builtin_amdgcn_cvt_pkrtz(a, b);
    return c.u;
}
__device__ __forceinline__ float f16b2f(unsigned short b) {
    union { unsigned short u; __fp16 h; } c; c.u = b; return (float)c.h;
}
__device__ __forceinline__ unsigned pkbf(float a, float b) {
    return (unsigned)f2bf(a) | ((unsigned)f2bf(b) << 16);
}
__device__ __forceinline__ float wred_max(float v) {
#pragma unroll
    for (int o = 32; o; o >>= 1) v = fmaxf(v, __shfl_xor(v, o));
    return v;
}
__device__ __forceinline__ float wred_sum(float v) {
#pragma unroll
    for (int o = 32; o; o >>= 1) v += __shfl_xor(v, o);
    return v;
}

// ---------------- f32 -> bf16 cast (n % 8 == 0) ----------------
__global__ __launch_bounds__(256) void cast_bf16(const float* __restrict__ in,
                                                 unsigned short* __restrict__ out, size_t n) {
    size_t i = ((size_t)blockIdx.x * 256 + threadIdx.x) * 8;
    if (i >= n) return;
    float4 v0 = *(const float4*)(in + i);
    float4 v1 = *(const float4*)(in + i + 4);
    union { unsigned short u[8]; uint4 q; } o;
    o.u[0] = f2bf(v0.x); o.u[1] = f2bf(v0.y); o.u[2] = f2bf(v0.z); o.u[3] = f2bf(v0.w);
    o.u[4] = f2bf(v1.x); o.u[5] = f2bf(v1.y); o.u[6] = f2bf(v1.z); o.u[7] = f2bf(v1.w);
    *(uint4*)(out + i) = o.q;
}

// ---------------- CSR build ----------------
__global__ __launch_bounds__(256) void count_deg(const int* __restrict__ dst,
                                                 int E, int Et, int* __restrict__ deg) {
    int e = blockIdx.x * blockDim.x + threadIdx.x;
    if (e >= Et) return;
    int d = (e < E) ? dst[e] : (e - E);
    atomicAdd(&deg[d], 1);
}

__global__ __launch_bounds__(256) void scan_p1(const int* __restrict__ deg,
                                               int* __restrict__ partial, int N) {
    __shared__ int ws[4];
    int tid = threadIdx.x, lane = tid & 63, w = tid >> 6;
    int idx = blockIdx.x * 256 + tid;
    int v = (idx < N) ? deg[idx] : 0;
    int s = v;
#pragma unroll
    for (int o = 32; o; o >>= 1) s += __shfl_xor(s, o);
    if (lane == 0) ws[w] = s;
    __syncthreads();
    if (tid == 0) partial[blockIdx.x] = ws[0] + ws[1] + ws[2] + ws[3];
}

__global__ __launch_bounds__(256) void scan_p2(int* __restrict__ partial, int nb) {
    __shared__ int ws[4];
    __shared__ int s_carry;
    int tid = threadIdx.x, lane = tid & 63, w = tid >> 6;
    if (tid == 0) s_carry = 0;
    __syncthreads();
    for (int base = 0; base < nb; base += 256) {
        int idx = base + tid;
        int v = (idx < nb) ? partial[idx] : 0;
        int incl = v;
#pragma unroll
        for (int off = 1; off < 64; off <<= 1) {
            int t = __shfl_up(incl, off);
            if (lane >= off) incl += t;
        }
        if (lane == 63) ws[w] = incl;
        __syncthreads();
        int wpre = 0;
        for (int k = 0; k < w; ++k) wpre += ws[k];
        int carry = s_carry;
        if (idx < nb) partial[idx] = carry + wpre + incl - v;
        __syncthreads();
        if (tid == 255) s_carry = carry + wpre + incl;
        __syncthreads();
    }
}

__global__ __launch_bounds__(256) void scan_p3(const int* __restrict__ deg,
                                               const int* __restrict__ partial,
                                               int* __restrict__ rowptr, int N, int Et) {
    __shared__ int ws[4];
    int tid = threadIdx.x, lane = tid & 63, w = tid >> 6;
    int idx = blockIdx.x * 256 + tid;
    int v = (idx < N) ? deg[idx] : 0;
    int incl = v;
#pragma unroll
    for (int off = 1; off < 64; off <<= 1) {
        int t = __shfl_up(incl, off);
        if (lane >= off) incl += t;
    }
    if (lane == 63) ws[w] = incl;
    __syncthreads();
    int wpre = 0;
    for (int k = 0; k < w; ++k) wpre += ws[k];
    if (idx < N) rowptr[idx] = partial[blockIdx.x] + wpre + incl - v;
    if (idx == N - 1) rowptr[N] = Et;
}

__global__ __launch_bounds__(256) void scatter_edges(const int* __restrict__ src,
                                                     const int* __restrict__ dst,
                                                     int E, int Et,
                                                     const int* __restrict__ rowptr,
                                                     int* __restrict__ cursor,
                                                     int* __restrict__ srcs) {
    int e = blockIdx.x * blockDim.x + threadIdx.x;
    if (e >= Et) return;
    int d = (e < E) ? dst[e] : (e - E);
    int s = (e < E) ? src[e] : (e - E);
    int pos = atomicAdd(&cursor[d], 1);
    srcs[rowptr[d] + pos] = s;
}

// ---------------- MFMA GEMM (bf16 out) + fused node_alpha ----------------
template<int M, int H>
__global__ __launch_bounds__(256) void gemm_mfma(const unsigned short* __restrict__ Ab,
                                                 const unsigned short* __restrict__ Wb,
                                                 const float* __restrict__ att_s,
                                                 const float* __restrict__ att_d,
                                                 unsigned short* __restrict__ Cb,
                                                 float* __restrict__ as_,
                                                 float* __restrict__ ad_,
                                                 int N) {
    constexpr int CT = M / 16;
    int tid = threadIdx.x;
    int wid = tid >> 6, l = tid & 63;
    int l15 = l & 15, lhi = l >> 4;
    int rowbase = blockIdx.x * 128 + wid * 32;
    f32x4 acc[2][CT] = {};

    int r0c = min(rowbase + l15, N - 1);
    int r1c = min(rowbase + 16 + l15, N - 1);
    const unsigned short* a0p = Ab + (size_t)r0c * 128 + lhi * 8;
    const unsigned short* a1p = Ab + (size_t)r1c * 128 + lhi * 8;
    const unsigned short* wp  = Wb + (size_t)l15 * 128 + lhi * 8;

#pragma unroll
    for (int ks = 0; ks < 4; ++ks) {
        int k0 = ks * 32;
        bf16x8 a0 = *reinterpret_cast<const bf16x8*>(a0p + k0);
        bf16x8 a1 = *reinterpret_cast<const bf16x8*>(a1p + k0);
#pragma unroll
        for (int ct = 0; ct < CT; ++ct) {
            bf16x8 b = *reinterpret_cast<const bf16x8*>(wp + (size_t)ct * 16 * 128 + k0);
            acc[0][ct] = __builtin_amdgcn_mfma_f32_16x16x32_bf16(a0, b, acc[0][ct], 0, 0, 0);
            acc[1][ct] = __builtin_amdgcn_mfma_f32_16x16x32_bf16(a1, b, acc[1][ct], 0, 0, 0);
        }
    }

#pragma unroll
    for (int rt = 0; rt < 2; ++rt) {
        int rbase = rowbase + rt * 16 + lhi * 4;
#pragma unroll
        for (int j = 0; j < 4; ++j) {
            int gr = rbase + j;
            if (gr < N) {
#pragma unroll
                for (int ct = 0; ct < CT; ++ct)
                    Cb[(size_t)gr * M + ct * 16 + l15] = f2bf(acc[rt][ct][j]);
            }
        }
#pragma unroll
        for (int hd = 0; hd < H; ++hd) {
            float ps0 = 0.f, ps1 = 0.f, ps2 = 0.f, ps3 = 0.f;
            float pd0 = 0.f, pd1 = 0.f, pd2 = 0.f, pd3 = 0.f;
#pragma unroll
            for (int c4 = 0; c4 < 4; ++c4) {
                int ct = hd * 4 + c4;
                float ws = att_s[hd * 64 + c4 * 16 + l15];
                float wd = att_d[hd * 64 + c4 * 16 + l15];
                ps0 += acc[rt][ct][0] * ws; pd0 += acc[rt][ct][0] * wd;
                ps1 += acc[rt][ct][1] * ws; pd1 += acc[rt][ct][1] * wd;
                ps2 += acc[rt][ct][2] * ws; pd2 += acc[rt][ct][2] * wd;
                ps3 += acc[rt][ct][3] * ws; pd3 += acc[rt][ct][3] * wd;
            }
#pragma unroll
            for (int o = 1; o < 16; o <<= 1) {
                ps0 += __shfl_xor(ps0, o); pd0 += __shfl_xor(pd0, o);
                ps1 += __shfl_xor(ps1, o); pd1 += __shfl_xor(pd1, o);
                ps2 += __shfl_xor(ps2, o); pd2 += __shfl_xor(pd2, o);
                ps3 += __shfl_xor(ps3, o); pd3 += __shfl_xor(pd3, o);
            }
            if (l15 == 0) {
                int gr = rbase;
                if (gr < N)     { as_[(size_t)gr * H + hd] = ps0; ad_[(size_t)gr * H + hd] = pd0; }
                if (gr + 1 < N) { as_[(size_t)(gr + 1) * H + hd] = ps1; ad_[(size_t)(gr + 1) * H + hd] = pd1; }
                if (gr + 2 < N) { as_[(size_t)(gr + 2) * H + hd] = ps2; ad_[(size_t)(gr + 2) * H + hd] = pd2; }
                if (gr + 3 < N) { as_[(size_t)(gr + 3) * H + hd] = ps3; ad_[(size_t)(gr + 3) * H + hd] = pd3; }
            }
        }
    }
}

// ---------------- fused softmax + aggregation (bf16 features, multi-edge) ----------------
// H=2: RW=64 u32 words/row. 32-lane groups, 2 edges/iter, uint2 loads (4 ch/lane). bf16 out.
// H=1: RW=32 u32 words/row. 16-lane groups, 4 edges/iter, uint2 loads (4 ch/lane). f32 out.
template<int H, bool DO_ELU>
__global__ __launch_bounds__(256) void gat_agg(const int* __restrict__ rowptr,
                                               const int* __restrict__ srcs,
                                               const float* __restrict__ as_,
                                               const float* __restrict__ ad_,
                                               const unsigned* __restrict__ hfeat,
                                               const float* __restrict__ bias,
                                               void* __restrict__ outp, int N) {
    constexpr int RW = 32 * H;          // u32 words per feature row
    constexpr int G  = (H == 2) ? 2 : 4; // edges in flight
    constexpr int GL = 64 / G;           // lanes per edge group
    int wid = threadIdx.x >> 6, lane = threadIdx.x & 63;
    int il = lane & (GL - 1);            // lane within group: covers ch 4*il..4*il+3
    int grp = lane / GL;                 // which edge in the G-pack
    int d = blockIdx.x * 4 + wid;
    if (d >= N) return;
    int r0 = rowptr[d], r1 = rowptr[d + 1];
    int cnt = r1 - r0;
    float uad[H];
#pragma unroll
    for (int h = 0; h < H; ++h) uad[h] = ad_[(size_t)d * H + h];
    float a0 = 0.f, a1 = 0.f, a2 = 0.f, a3 = 0.f;

    if (cnt <= 64) {
        int i = r0 + lane;
        bool act = i < r1;
        int se = act ? srcs[i] : 0;
        float ax[H];
#pragma unroll
        for (int h = 0; h < H; ++h) {
            float sc = act ? lrelu(as_[(size_t)se * H + h] + uad[h]) : -3.4e38f;
            float m = wred_max(sc);
            float ex = act ? expf(sc - m) : 0.f;
            float den = wred_sum(ex);
            ax[h] = ex / (den + 1e-16f);
        }
        int base_w = se * RW;
        if (H == 2) {
            unsigned apk = pkf16(ax[0], ax[H - 1]);
            for (int t = 0; t < cnt; t += G) {
                int tr = t + grp;
                int tt = tr & 63;
                int bw = __shfl(base_w, tt);
                unsigned au = __shfl(apk, tt);
                float af = (tr < cnt)
                    ? f16b2f((unsigned short)((il < 16) ? (au & 0xffff) : (au >> 16))) : 0.f;
                uint2 u = *(const uint2*)(hfeat + bw + 2 * il);
                a0 += af * bf16lo(u.x); a1 += af * bf16hi(u.x);
                a2 += af * bf16lo(u.y); a3 += af * bf16hi(u.y);
            }
        } else {
            float ax0 = ax[0];
            for (int t = 0; t < cnt; t += G) {
                int tr = t + grp;
                int tt = tr & 63;
                int bw = __shfl(base_w, tt);
                float af = __shfl(ax0, tt);
                if (tr >= cnt) af = 0.f;
                uint2 u = *(const uint2*)(hfeat + bw + 2 * il);
                a0 += af * bf16lo(u.x); a1 += af * bf16hi(u.x);
                a2 += af * bf16lo(u.y); a3 += af * bf16hi(u.y);
            }
        }
    } else {
        // generic chunked path (deg > 64) -- statistically never, correctness only
        float mx[H];
#pragma unroll
        for (int h = 0; h < H; ++h) mx[h] = -3.4e38f;
        for (int base = r0; base < r1; base += 64) {
            int i = base + lane;
            bool act = i < r1;
            int s = act ? srcs[i] : 0;
#pragma unroll
            for (int h = 0; h < H; ++h) {
                float sc = act ? lrelu(as_[(size_t)s * H + h] + uad[h]) : -3.4e38f;
                mx[h] = fmaxf(mx[h], sc);
            }
        }
#pragma unroll
        for (int h = 0; h < H; ++h) mx[h] = wred_max(mx[h]);
        float den[H] = {};
        for (int base = r0; base < r1; base += 64) {
            int i = base + lane;
            bool act = i < r1;
            int s = act ? srcs[i] : 0;
#pragma unroll
            for (int h = 0; h < H; ++h)
                den[h] += act ? expf(lrelu(as_[(size_t)s * H + h] + uad[h]) - mx[h]) : 0.f;
        }
        float inv[H];
#pragma unroll
        for (int h = 0; h < H; ++h) inv[h] = 1.f / (wred_sum(den[h]) + 1e-16f);
        for (int base = r0; base < r1; base += 64) {
            int i = base + lane;
            bool act = i < r1;
            int se = act ? srcs[i] : 0;
            float ax[H];
#pragma unroll
            for (int h = 0; h < H; ++h)
                ax[h] = act ? expf(lrelu(as_[(size_t)se * H + h] + uad[h]) - mx[h]) * inv[h] : 0.f;
            int cntc = min(64, r1 - base);
            int base_w = se * RW;
            if (H == 2) {
                unsigned apk = pkf16(ax[0], ax[H - 1]);
                for (int t = 0; t < cntc; t += G) {
                    int tr = t + grp;
                    int tt = tr & 63;
                    int bw = __shfl(base_w, tt);
                    unsigned au = __shfl(apk, tt);
                    float af = (tr < cntc)
                        ? f16b2f((unsigned short)((il < 16) ? (au & 0xffff) : (au >> 16))) : 0.f;
                    uint2 u = *(const uint2*)(hfeat + bw + 2 * il);
                    a0 += af * bf16lo(u.x); a1 += af * bf16hi(u.x);
                    a2 += af * bf16lo(u.y); a3 += af * bf16hi(u.y);
                }
            } else {
                float ax0 = ax[0];
                for (int t = 0; t < cntc; t += G) {
                    int tr = t + grp;
                    int tt = tr & 63;
                    int bw = __shfl(base_w, tt);
                    float af = __shfl(ax0, tt);
                    if (tr >= cntc) af = 0.f;
                    uint2 u = *(const uint2*)(hfeat + bw + 2 * il);
                    a0 += af * bf16lo(u.x); a1 += af * bf16hi(u.x);
                    a2 += af * bf16lo(u.y); a3 += af * bf16hi(u.y);
                }
            }
        }
    }

    // cross-group reduction
#pragma unroll
    for (int o = GL; o < 64; o <<= 1) {
        a0 += __shfl_xor(a0, o);
        a1 += __shfl_xor(a1, o);
        a2 += __shfl_xor(a2, o);
        a3 += __shfl_xor(a3, o);
    }
    if (grp == 0) {
        int c0 = 4 * il;
        float4 b4 = *(const float4*)(bias + c0);
        float v0 = a0 + b4.x, v1 = a1 + b4.y, v2 = a2 + b4.z, v3 = a3 + b4.w;
        if (DO_ELU) {
            v0 = v0 > 0.f ? v0 : expm1f(v0);
            v1 = v1 > 0.f ? v1 : expm1f(v1);
            v2 = v2 > 0.f ? v2 : expm1f(v2);
            v3 = v3 > 0.f ? v3 : expm1f(v3);
        }
        if (H == 2) {
            uint2 o;
            o.x = pkbf(v0, v1);
            o.y = pkbf(v2, v3);
            *(uint2*)((unsigned*)outp + (size_t)d * RW + 2 * il) = o;
        } else {
            float4 o = make_float4(v0, v1, v2, v3);
            *(float4*)((float*)outp + (size_t)d * 64 + c0) = o;
        }
    }
}

extern "C" void kernel_launch(void* const* d_in, const int* in_sizes, int n_in,
                              void* d_out, int out_size, void* d_ws, size_t ws_size,
                              hipStream_t stream) {
    const float* x   = (const float*)d_in[0];
    const int*   ei  = (const int*)d_in[1];
    const float* W1  = (const float*)d_in[2];
    const float* a1s = (const float*)d_in[3];
    const float* a1d = (const float*)d_in[4];
    const float* b1  = (const float*)d_in[5];
    const float* W2  = (const float*)d_in[6];
    const float* a2s = (const float*)d_in[7];
    const float* a2d = (const float*)d_in[8];
    const float* b2  = (const float*)d_in[9];
    float* out = (float*)d_out;

    int N  = in_sizes[0] / 128;
    int E  = in_sizes[1] / 2;
    int Et = E + N;
    const int* src = ei;
    const int* dst = ei + E;
    int nb = (N + 255) / 256;

    char* p = (char*)d_ws;
    unsigned short* xb = (unsigned short*)p;    p += (size_t)N * 128 * 2;
    unsigned short* h1b = (unsigned short*)p;   p += (size_t)N * 128 * 2;
    unsigned short* act1b = (unsigned short*)p; p += (size_t)N * 128 * 2;
    unsigned short* w1b = (unsigned short*)p;   p += 128 * 128 * 2;
    unsigned short* w2b = (unsigned short*)p;   p += 64 * 128 * 2;
    float* as1 = (float*)p;                p += (size_t)N * 2 * 4;
    float* ad1 = (float*)p;                p += (size_t)N * 2 * 4;
    float* as2 = (float*)p;                p += (size_t)N * 4;
    float* ad2 = (float*)p;                p += (size_t)N * 4;
    int* rowptr = (int*)p;                 p += (size_t)(N + 1) * 4;
    int* deg = (int*)p;                    p += (size_t)N * 4;
    int* partial = (int*)p;                p += (size_t)nb * 4;
    int* srcs = (int*)p;                   p += (size_t)Et * 4;
    unsigned short* h2b = xb;              // alias: xb dead after gemm1

    // ---- CSR build ----
    hipMemsetAsync(deg, 0, (size_t)N * 4, stream);
    count_deg<<<(Et + 255) / 256, 256, 0, stream>>>(dst, E, Et, deg);
    scan_p1<<<nb, 256, 0, stream>>>(deg, partial, N);
    scan_p2<<<1, 256, 0, stream>>>(partial, nb);
    scan_p3<<<nb, 256, 0, stream>>>(deg, partial, rowptr, N, Et);
    hipMemsetAsync(deg, 0, (size_t)N * 4, stream);
    scatter_edges<<<(Et + 255) / 256, 256, 0, stream>>>(src, dst, E, Et, rowptr, deg, srcs);

    // ---- casts ----
    cast_bf16<<<((size_t)N * 128 / 8 + 255) / 256, 256, 0, stream>>>(x, xb, (size_t)N * 128);
    cast_bf16<<<(128 * 128 / 8 + 255) / 256, 256, 0, stream>>>(W1, w1b, 128 * 128);
    cast_bf16<<<(64 * 128 / 8 + 255) / 256, 256, 0, stream>>>(W2, w2b, 64 * 128);

    // ---- layer 1 ----
    gemm_mfma<128, 2><<<(N + 127) / 128, 256, 0, stream>>>(xb, w1b, a1s, a1d, h1b, as1, ad1, N);
    gat_agg<2, true><<<(N + 3) / 4, 256, 0, stream>>>(rowptr, srcs, as1, ad1,
                                                      (const unsigned*)h1b, b1, act1b, N);

    // ---- layer 2 ----
    gemm_mfma<64, 1><<<(N + 127) / 128, 256, 0, stream>>>(act1b, w2b, a2s, a2d, h2b, as2, ad2, N);
    gat_agg<1, false><<<(N + 3) / 4, 256, 0, stream>>>(rowptr, srcs, as2, ad2,
                                                       (const unsigned*)h2b, b2, out, N);
}

// Round 8
// 223.231 us; speedup vs baseline: 5.2678x; 1.0147x over previous
//
#include <hip/hip_runtime.h>
#include <hip/hip_bf16.h>
#include <math.h>

typedef __bf16 bf16x8 __attribute__((ext_vector_type(8)));
typedef float f32x4 __attribute__((ext_vector_type(4)));
typedef __fp16 fp16x2 __attribute__((ext_vector_type(2)));

__device__ __forceinline__ float lrelu(float x) { return x > 0.f ? x : 0.2f * x; }
__device__ __forceinline__ unsigned short f2bf(float f) {
    unsigned u = __float_as_uint(f);
    return (unsigned short)((u + 0x7fffu + ((u >> 16) & 1u)) >> 16);
}
__device__ __forceinline__ float bf16lo(unsigned u) { return __uint_as_float(u << 16); }
__device__ __forceinline__ float bf16hi(unsigned u) { return __uint_as_float(u & 0xffff0000u); }
__device__ __forceinline__ unsigned pkf16(float a, float b) {
    union { fp16x2 h; unsigned u; } c;
    c.h = __builtin_amdgcn_cvt_pkrtz(a, b);
    return c.u;
}
__device__ __forceinline__ float f16b2f(unsigned short b) {
    union { unsigned short u; __fp16 h; } c; c.u = b; return (float)c.h;
}
__device__ __forceinline__ unsigned pkbf(float a, float b) {
    return (unsigned)f2bf(a) | ((unsigned)f2bf(b) << 16);
}
__device__ __forceinline__ float wred_max(float v) {
#pragma unroll
    for (int o = 32; o; o >>= 1) v = fmaxf(v, __shfl_xor(v, o));
    return v;
}
__device__ __forceinline__ float wred_sum(float v) {
#pragma unroll
    for (int o = 32; o; o >>= 1) v += __shfl_xor(v, o);
    return v;
}

// ---------------- f32 -> bf16 cast (n % 8 == 0) ----------------
__global__ __launch_bounds__(256) void cast_bf16(const float* __restrict__ in,
                                                 unsigned short* __restrict__ out, size_t n) {
    size_t i = ((size_t)blockIdx.x * 256 + threadIdx.x) * 8;
    if (i >= n) return;
    float4 v0 = *(const float4*)(in + i);
    float4 v1 = *(const float4*)(in + i + 4);
    union { unsigned short u[8]; uint4 q; } o;
    o.u[0] = f2bf(v0.x); o.u[1] = f2bf(v0.y); o.u[2] = f2bf(v0.z); o.u[3] = f2bf(v0.w);
    o.u[4] = f2bf(v1.x); o.u[5] = f2bf(v1.y); o.u[6] = f2bf(v1.z); o.u[7] = f2bf(v1.w);
    *(uint4*)(out + i) = o.q;
}

// ---------------- CSR build ----------------
__global__ __launch_bounds__(256) void count_deg(const int* __restrict__ dst,
                                                 int E, int Et, int* __restrict__ deg) {
    int e = blockIdx.x * blockDim.x + threadIdx.x;
    if (e >= Et) return;
    int d = (e < E) ? dst[e] : (e - E);
    atomicAdd(&deg[d], 1);
}

__global__ __launch_bounds__(256) void scan_p1(const int* __restrict__ deg,
                                               int* __restrict__ partial, int N) {
    __shared__ int ws[4];
    int tid = threadIdx.x, lane = tid & 63, w = tid >> 6;
    int idx = blockIdx.x * 256 + tid;
    int v = (idx < N) ? deg[idx] : 0;
    int s = v;
#pragma unroll
    for (int o = 32; o; o >>= 1) s += __shfl_xor(s, o);
    if (lane == 0) ws[w] = s;
    __syncthreads();
    if (tid == 0) partial[blockIdx.x] = ws[0] + ws[1] + ws[2] + ws[3];
}

__global__ __launch_bounds__(256) void scan_p2(int* __restrict__ partial, int nb) {
    __shared__ int ws[4];
    __shared__ int s_carry;
    int tid = threadIdx.x, lane = tid & 63, w = tid >> 6;
    if (tid == 0) s_carry = 0;
    __syncthreads();
    for (int base = 0; base < nb; base += 256) {
        int idx = base + tid;
        int v = (idx < nb) ? partial[idx] : 0;
        int incl = v;
#pragma unroll
        for (int off = 1; off < 64; off <<= 1) {
            int t = __shfl_up(incl, off);
            if (lane >= off) incl += t;
        }
        if (lane == 63) ws[w] = incl;
        __syncthreads();
        int wpre = 0;
        for (int k = 0; k < w; ++k) wpre += ws[k];
        int carry = s_carry;
        if (idx < nb) partial[idx] = carry + wpre + incl - v;
        __syncthreads();
        if (tid == 255) s_carry = carry + wpre + incl;
        __syncthreads();
    }
}

__global__ __launch_bounds__(256) void scan_p3(const int* __restrict__ deg,
                                               const int* __restrict__ partial,
                                               int* __restrict__ rowptr, int N, int Et) {
    __shared__ int ws[4];
    int tid = threadIdx.x, lane = tid & 63, w = tid >> 6;
    int idx = blockIdx.x * 256 + tid;
    int v = (idx < N) ? deg[idx] : 0;
    int incl = v;
#pragma unroll
    for (int off = 1; off < 64; off <<= 1) {
        int t = __shfl_up(incl, off);
        if (lane >= off) incl += t;
    }
    if (lane == 63) ws[w] = incl;
    __syncthreads();
    int wpre = 0;
    for (int k = 0; k < w; ++k) wpre += ws[k];
    if (idx < N) rowptr[idx] = partial[blockIdx.x] + wpre + incl - v;
    if (idx == N - 1) rowptr[N] = Et;
}

__global__ __launch_bounds__(256) void scatter_edges(const int* __restrict__ src,
                                                     const int* __restrict__ dst,
                                                     int E, int Et,
                                                     const int* __restrict__ rowptr,
                                                     int* __restrict__ cursor,
                                                     int* __restrict__ srcs) {
    int e = blockIdx.x * blockDim.x + threadIdx.x;
    if (e >= Et) return;
    int d = (e < E) ? dst[e] : (e - E);
    int s = (e < E) ? src[e] : (e - E);
    int pos = atomicAdd(&cursor[d], 1);
    srcs[rowptr[d] + pos] = s;
}

// ---------------- MFMA GEMM (bf16 out) + fused node_alpha, 16 rows/wave ----------------
template<int M, int H>
__global__ __launch_bounds__(256) void gemm_mfma(const unsigned short* __restrict__ Ab,
                                                 const unsigned short* __restrict__ Wb,
                                                 const float* __restrict__ att_s,
                                                 const float* __restrict__ att_d,
                                                 unsigned short* __restrict__ Cb,
                                                 float* __restrict__ as_,
                                                 float* __restrict__ ad_,
                                                 int N) {
    constexpr int CT = M / 16;
    int tid = threadIdx.x;
    int wid = tid >> 6, l = tid & 63;
    int l15 = l & 15, lhi = l >> 4;
    int rowbase = blockIdx.x * 64 + wid * 16;
    f32x4 acc[CT] = {};

    int rc = min(rowbase + l15, N - 1);
    const unsigned short* ap = Ab + (size_t)rc * 128 + lhi * 8;
    const unsigned short* wp = Wb + (size_t)l15 * 128 + lhi * 8;

#pragma unroll
    for (int ks = 0; ks < 4; ++ks) {
        int k0 = ks * 32;
        bf16x8 a = *reinterpret_cast<const bf16x8*>(ap + k0);
#pragma unroll
        for (int ct = 0; ct < CT; ++ct) {
            bf16x8 b = *reinterpret_cast<const bf16x8*>(wp + (size_t)ct * 16 * 128 + k0);
            acc[ct] = __builtin_amdgcn_mfma_f32_16x16x32_bf16(a, b, acc[ct], 0, 0, 0);
        }
    }

    int rbase = rowbase + lhi * 4;
#pragma unroll
    for (int j = 0; j < 4; ++j) {
        int gr = rbase + j;
        if (gr < N) {
#pragma unroll
            for (int ct = 0; ct < CT; ++ct)
                Cb[(size_t)gr * M + ct * 16 + l15] = f2bf(acc[ct][j]);
        }
    }
#pragma unroll
    for (int hd = 0; hd < H; ++hd) {
        float ps0 = 0.f, ps1 = 0.f, ps2 = 0.f, ps3 = 0.f;
        float pd0 = 0.f, pd1 = 0.f, pd2 = 0.f, pd3 = 0.f;
#pragma unroll
        for (int c4 = 0; c4 < 4; ++c4) {
            int ct = hd * 4 + c4;
            float ws = att_s[hd * 64 + c4 * 16 + l15];
            float wd = att_d[hd * 64 + c4 * 16 + l15];
            ps0 += acc[ct][0] * ws; pd0 += acc[ct][0] * wd;
            ps1 += acc[ct][1] * ws; pd1 += acc[ct][1] * wd;
            ps2 += acc[ct][2] * ws; pd2 += acc[ct][2] * wd;
            ps3 += acc[ct][3] * ws; pd3 += acc[ct][3] * wd;
        }
#pragma unroll
        for (int o = 1; o < 16; o <<= 1) {
            ps0 += __shfl_xor(ps0, o); pd0 += __shfl_xor(pd0, o);
            ps1 += __shfl_xor(ps1, o); pd1 += __shfl_xor(pd1, o);
            ps2 += __shfl_xor(ps2, o); pd2 += __shfl_xor(pd2, o);
            ps3 += __shfl_xor(ps3, o); pd3 += __shfl_xor(pd3, o);
        }
        if (l15 == 0) {
            int gr = rbase;
            if (gr < N)     { as_[(size_t)gr * H + hd] = ps0; ad_[(size_t)gr * H + hd] = pd0; }
            if (gr + 1 < N) { as_[(size_t)(gr + 1) * H + hd] = ps1; ad_[(size_t)(gr + 1) * H + hd] = pd1; }
            if (gr + 2 < N) { as_[(size_t)(gr + 2) * H + hd] = ps2; ad_[(size_t)(gr + 2) * H + hd] = pd2; }
            if (gr + 3 < N) { as_[(size_t)(gr + 3) * H + hd] = ps3; ad_[(size_t)(gr + 3) * H + hd] = pd3; }
        }
    }
}

// ---------------- fused softmax + aggregation (bf16 features, LDS-staged alpha) --------
// Per dst wave. Edge metadata {row_word_offset, alpha} staged in LDS.
// H=2: 16 lanes/edge, 4 edges/iter, uint4 loads (8 ch/lane), bf16 out.
// H=1: 8 lanes/edge, 8 edges/iter, uint4 loads (8 ch/lane), f32 out.
template<int H, bool DO_ELU>
__global__ __launch_bounds__(256) void gat_agg(const int* __restrict__ rowptr,
                                               const int* __restrict__ srcs,
                                               const float* __restrict__ as_,
                                               const float* __restrict__ ad_,
                                               const unsigned* __restrict__ hfeat,
                                               const float* __restrict__ bias,
                                               void* __restrict__ outp, int N) {
    constexpr int RW = 32 * H;            // u32 words per feature row
    constexpr int G  = (H == 2) ? 4 : 8;  // edges per iteration
    constexpr int GL = 64 / G;            // lanes per edge
    __shared__ uint2 sent[4][72];
    int wid = threadIdx.x >> 6, lane = threadIdx.x & 63;
    int il = lane & (GL - 1);
    int grp = lane >> ((H == 2) ? 4 : 3);
    int d = blockIdx.x * 4 + wid;
    if (d >= N) return;
    if (lane < 8) sent[wid][64 + lane] = make_uint2(0u, 0u);
    int r0 = rowptr[d], r1 = rowptr[d + 1];
    int cnt = r1 - r0;
    float uad[H];
#pragma unroll
    for (int h = 0; h < H; ++h) uad[h] = ad_[(size_t)d * H + h];
    float a0 = 0.f, a1 = 0.f, a2 = 0.f, a3 = 0.f, a4 = 0.f, a5 = 0.f, a6 = 0.f, a7 = 0.f;
    const unsigned* hfl = hfeat + 4 * il;     // lane-fixed word offset
    bool hhi = (H == 2) && (il >= 8);         // which head this lane's channels belong to

    if (cnt <= 64) {
        int i = r0 + lane;
        bool act = i < r1;
        int se = act ? srcs[i] : 0;
        float ax[H];
#pragma unroll
        for (int h = 0; h < H; ++h) {
            float sc = act ? lrelu(as_[(size_t)se * H + h] + uad[h]) : -3.4e38f;
            float m = wred_max(sc);
            float ex = act ? expf(sc - m) : 0.f;
            float den = wred_sum(ex);
            ax[h] = ex / (den + 1e-16f);
        }
        unsigned pk = (H == 2) ? pkf16(ax[0], ax[H - 1]) : __float_as_uint(ax[0]);
        sent[wid][lane] = make_uint2((unsigned)(se * RW), pk);
        __threadfence_block();
#pragma unroll 2
        for (int t = 0; t < cnt; t += G) {
            uint2 en = sent[wid][t + grp];
            float af = (H == 2)
                ? f16b2f((unsigned short)(hhi ? (en.y >> 16) : (en.y & 0xffffu)))
                : __uint_as_float(en.y);
            uint4 u = *(const uint4*)(hfl + en.x);
            a0 += af * bf16lo(u.x); a1 += af * bf16hi(u.x);
            a2 += af * bf16lo(u.y); a3 += af * bf16hi(u.y);
            a4 += af * bf16lo(u.z); a5 += af * bf16hi(u.z);
            a6 += af * bf16lo(u.w); a7 += af * bf16hi(u.w);
        }
    } else {
        // generic chunked path (deg > 64) -- statistically never, correctness only
        float mx[H];
#pragma unroll
        for (int h = 0; h < H; ++h) mx[h] = -3.4e38f;
        for (int base = r0; base < r1; base += 64) {
            int i = base + lane;
            bool act = i < r1;
            int s = act ? srcs[i] : 0;
#pragma unroll
            for (int h = 0; h < H; ++h) {
                float sc = act ? lrelu(as_[(size_t)s * H + h] + uad[h]) : -3.4e38f;
                mx[h] = fmaxf(mx[h], sc);
            }
        }
#pragma unroll
        for (int h = 0; h < H; ++h) mx[h] = wred_max(mx[h]);
        float den[H] = {};
        for (int base = r0; base < r1; base += 64) {
            int i = base + lane;
            bool act = i < r1;
            int s = act ? srcs[i] : 0;
#pragma unroll
            for (int h = 0; h < H; ++h)
                den[h] += act ? expf(lrelu(as_[(size_t)s * H + h] + uad[h]) - mx[h]) : 0.f;
        }
        float inv[H];
#pragma unroll
        for (int h = 0; h < H; ++h) inv[h] = 1.f / (wred_sum(den[h]) + 1e-16f);
        for (int base = r0; base < r1; base += 64) {
            int i = base + lane;
            bool act = i < r1;
            int se = act ? srcs[i] : 0;
            float ax[H];
#pragma unroll
            for (int h = 0; h < H; ++h)
                ax[h] = act ? expf(lrelu(as_[(size_t)se * H + h] + uad[h]) - mx[h]) * inv[h] : 0.f;
            int cntc = min(64, r1 - base);
            unsigned pk = (H == 2) ? pkf16(ax[0], ax[H - 1]) : __float_as_uint(ax[0]);
            sent[wid][lane] = make_uint2((unsigned)(se * RW), pk);
            __threadfence_block();
            for (int t = 0; t < cntc; t += G) {
                uint2 en = sent[wid][t + grp];
                float af = (H == 2)
                    ? f16b2f((unsigned short)(hhi ? (en.y >> 16) : (en.y & 0xffffu)))
                    : __uint_as_float(en.y);
                uint4 u = *(const uint4*)(hfl + en.x);
                a0 += af * bf16lo(u.x); a1 += af * bf16hi(u.x);
                a2 += af * bf16lo(u.y); a3 += af * bf16hi(u.y);
                a4 += af * bf16lo(u.z); a5 += af * bf16hi(u.z);
                a6 += af * bf16lo(u.w); a7 += af * bf16hi(u.w);
            }
            __threadfence_block();
        }
    }

    // cross-group reduction
#pragma unroll
    for (int o = GL; o < 64; o <<= 1) {
        a0 += __shfl_xor(a0, o); a1 += __shfl_xor(a1, o);
        a2 += __shfl_xor(a2, o); a3 += __shfl_xor(a3, o);
        a4 += __shfl_xor(a4, o); a5 += __shfl_xor(a5, o);
        a6 += __shfl_xor(a6, o); a7 += __shfl_xor(a7, o);
    }
    if (grp == 0) {
        int c0 = 8 * il;
        float4 bA = *(const float4*)(bias + c0);
        float4 bB = *(const float4*)(bias + c0 + 4);
        float v0 = a0 + bA.x, v1 = a1 + bA.y, v2 = a2 + bA.z, v3 = a3 + bA.w;
        float v4 = a4 + bB.x, v5 = a5 + bB.y, v6 = a6 + bB.z, v7 = a7 + bB.w;
        if (DO_ELU) {
            v0 = v0 > 0.f ? v0 : expm1f(v0); v1 = v1 > 0.f ? v1 : expm1f(v1);
            v2 = v2 > 0.f ? v2 : expm1f(v2); v3 = v3 > 0.f ? v3 : expm1f(v3);
            v4 = v4 > 0.f ? v4 : expm1f(v4); v5 = v5 > 0.f ? v5 : expm1f(v5);
            v6 = v6 > 0.f ? v6 : expm1f(v6); v7 = v7 > 0.f ? v7 : expm1f(v7);
        }
        if (H == 2) {
            uint4 o;
            o.x = pkbf(v0, v1); o.y = pkbf(v2, v3);
            o.z = pkbf(v4, v5); o.w = pkbf(v6, v7);
            *(uint4*)((unsigned*)outp + (size_t)d * 64 + 4 * il) = o;
        } else {
            *(float4*)((float*)outp + (size_t)d * 64 + c0) = make_float4(v0, v1, v2, v3);
            *(float4*)((float*)outp + (size_t)d * 64 + c0 + 4) = make_float4(v4, v5, v6, v7);
        }
    }
}

extern "C" void kernel_launch(void* const* d_in, const int* in_sizes, int n_in,
                              void* d_out, int out_size, void* d_ws, size_t ws_size,
                              hipStream_t stream) {
    const float* x   = (const float*)d_in[0];
    const int*   ei  = (const int*)d_in[1];
    const float* W1  = (const float*)d_in[2];
    const float* a1s = (const float*)d_in[3];
    const float* a1d = (const float*)d_in[4];
    const float* b1  = (const float*)d_in[5];
    const float* W2  = (const float*)d_in[6];
    const float* a2s = (const float*)d_in[7];
    const float* a2d = (const float*)d_in[8];
    const float* b2  = (const float*)d_in[9];
    float* out = (float*)d_out;

    int N  = in_sizes[0] / 128;
    int E  = in_sizes[1] / 2;
    int Et = E + N;
    const int* src = ei;
    const int* dst = ei + E;
    int nb = (N + 255) / 256;

    char* p = (char*)d_ws;
    unsigned short* xb = (unsigned short*)p;    p += (size_t)N * 128 * 2;
    unsigned short* h1b = (unsigned short*)p;   p += (size_t)N * 128 * 2;
    unsigned short* act1b = (unsigned short*)p; p += (size_t)N * 128 * 2;
    unsigned short* w1b = (unsigned short*)p;   p += 128 * 128 * 2;
    unsigned short* w2b = (unsigned short*)p;   p += 64 * 128 * 2;
    float* as1 = (float*)p;                p += (size_t)N * 2 * 4;
    float* ad1 = (float*)p;                p += (size_t)N * 2 * 4;
    float* as2 = (float*)p;                p += (size_t)N * 4;
    float* ad2 = (float*)p;                p += (size_t)N * 4;
    int* rowptr = (int*)p;                 p += (size_t)(N + 1) * 4;
    int* deg = (int*)p;                    p += (size_t)N * 4;
    int* partial = (int*)p;                p += (size_t)nb * 4;
    int* srcs = (int*)p;                   p += (size_t)Et * 4;
    unsigned short* h2b = xb;              // alias: xb dead after gemm1

    // ---- CSR build ----
    hipMemsetAsync(deg, 0, (size_t)N * 4, stream);
    count_deg<<<(Et + 255) / 256, 256, 0, stream>>>(dst, E, Et, deg);
    scan_p1<<<nb, 256, 0, stream>>>(deg, partial, N);
    scan_p2<<<1, 256, 0, stream>>>(partial, nb);
    scan_p3<<<nb, 256, 0, stream>>>(deg, partial, rowptr, N, Et);
    hipMemsetAsync(deg, 0, (size_t)N * 4, stream);
    scatter_edges<<<(Et + 255) / 256, 256, 0, stream>>>(src, dst, E, Et, rowptr, deg, srcs);

    // ---- casts ----
    cast_bf16<<<((size_t)N * 128 / 8 + 255) / 256, 256, 0, stream>>>(x, xb, (size_t)N * 128);
    cast_bf16<<<(128 * 128 / 8 + 255) / 256, 256, 0, stream>>>(W1, w1b, 128 * 128);
    cast_bf16<<<(64 * 128 / 8 + 255) / 256, 256, 0, stream>>>(W2, w2b, 64 * 128);

    // ---- layer 1 ----
    gemm_mfma<128, 2><<<(N + 63) / 64, 256, 0, stream>>>(xb, w1b, a1s, a1d, h1b, as1, ad1, N);
    gat_agg<2, true><<<(N + 3) / 4, 256, 0, stream>>>(rowptr, srcs, as1, ad1,
                                                      (const unsigned*)h1b, b1, act1b, N);

    // ---- layer 2 ----
    gemm_mfma<64, 1><<<(N + 63) / 64, 256, 0, stream>>>(act1b, w2b, a2s, a2d, h2b, as2, ad2, N);
    gat_agg<1, false><<<(N + 3) / 4, 256, 0, stream>>>(rowptr, srcs, as2, ad2,
                                                       (const unsigned*)h2b, b2, out, N);
}

// Round 9
// 159.132 us; speedup vs baseline: 7.3897x; 1.4028x over previous
//
#include <hip/hip_runtime.h>
#include <hip/hip_bf16.h>
#include <math.h>

typedef __bf16 bf16x8 __attribute__((ext_vector_type(8)));
typedef float f32x4 __attribute__((ext_vector_type(4)));
typedef __fp16 fp16x2 __attribute__((ext_vector_type(2)));

__device__ __forceinline__ float lrelu(float x) { return x > 0.f ? x : 0.2f * x; }
__device__ __forceinline__ unsigned short f2bf(float f) {
    unsigned u = __float_as_uint(f);
    return (unsigned short)((u + 0x7fffu + ((u >> 16) & 1u)) >> 16);
}
__device__ __forceinline__ float bf16lo(unsigned u) { return __uint_as_float(u << 16); }
__device__ __forceinline__ float bf16hi(unsigned u) { return __uint_as_float(u & 0xffff0000u); }
__device__ __forceinline__ unsigned pkf16(float a, float b) {
    union { fp16x2 h; unsigned u; } c;
    c.h = __builtin_amdgcn_cvt_pkrtz(a, b);
    return c.u;
}
__device__ __forceinline__ float f16b2f(unsigned short b) {
    union { unsigned short u; __fp16 h; } c; c.u = b; return (float)c.h;
}
__device__ __forceinline__ unsigned pkbf(float a, float b) {
    return (unsigned)f2bf(a) | ((unsigned)f2bf(b) << 16);
}
__device__ __forceinline__ float wred_max(float v) {
#pragma unroll
    for (int o = 32; o; o >>= 1) v = fmaxf(v, __shfl_xor(v, o));
    return v;
}
__device__ __forceinline__ float wred_sum(float v) {
#pragma unroll
    for (int o = 32; o; o >>= 1) v += __shfl_xor(v, o);
    return v;
}

// ---------------- f32 -> bf16 cast (n % 8 == 0) ----------------
__global__ __launch_bounds__(256) void cast_bf16(const float* __restrict__ in,
                                                 unsigned short* __restrict__ out, size_t n) {
    size_t i = ((size_t)blockIdx.x * 256 + threadIdx.x) * 8;
    if (i >= n) return;
    float4 v0 = *(const float4*)(in + i);
    float4 v1 = *(const float4*)(in + i + 4);
    union { unsigned short u[8]; uint4 q; } o;
    o.u[0] = f2bf(v0.x); o.u[1] = f2bf(v0.y); o.u[2] = f2bf(v0.z); o.u[3] = f2bf(v0.w);
    o.u[4] = f2bf(v1.x); o.u[5] = f2bf(v1.y); o.u[6] = f2bf(v1.z); o.u[7] = f2bf(v1.w);
    *(uint4*)(out + i) = o.q;
}

// ================= CSR build: two-level bucket sort, no global atomics =================
// coarse digit = dst >> 8 (256 buckets), fine digit = dst & 255.
// phase1: 4096 edges/block. k1: LDS hist -> g_hist[digit*NB + b].
//         scan (bucket-major). k3: LDS-stage sorted-by-digit, coalesced write to tmp.
// phase2: one block per coarse bucket: sub-hist + scan -> rowptr + place srcs.

__global__ __launch_bounds__(256) void k1_hist(const int* __restrict__ ei, int E, int Et,
                                               int* __restrict__ g_hist, int NB) {
    __shared__ int hist[256];
    int tid = threadIdx.x, b = blockIdx.x;
    hist[tid] = 0;
    __syncthreads();
    int base = b * 4096;
#pragma unroll
    for (int k = 0; k < 16; ++k) {
        int e = base + k * 256 + tid;
        if (e < Et) {
            int d = (e < E) ? ei[E + e] : (e - E);
            atomicAdd(&hist[d >> 8], 1);
        }
    }
    __syncthreads();
    g_hist[tid * NB + b] = hist[tid];
}

__global__ __launch_bounds__(256) void scan_p1(const int* __restrict__ in,
                                               int* __restrict__ partial, int n) {
    __shared__ int ws[4];
    int tid = threadIdx.x, lane = tid & 63, w = tid >> 6;
    int idx = blockIdx.x * 256 + tid;
    int v = (idx < n) ? in[idx] : 0;
    int s = v;
#pragma unroll
    for (int o = 32; o; o >>= 1) s += __shfl_xor(s, o);
    if (lane == 0) ws[w] = s;
    __syncthreads();
    if (tid == 0) partial[blockIdx.x] = ws[0] + ws[1] + ws[2] + ws[3];
}

__global__ __launch_bounds__(256) void scan_p2(int* __restrict__ partial, int nb) {
    __shared__ int ws[4];
    __shared__ int s_carry;
    int tid = threadIdx.x, lane = tid & 63, w = tid >> 6;
    if (tid == 0) s_carry = 0;
    __syncthreads();
    for (int base = 0; base < nb; base += 256) {
        int idx = base + tid;
        int v = (idx < nb) ? partial[idx] : 0;
        int incl = v;
#pragma unroll
        for (int off = 1; off < 64; off <<= 1) {
            int t = __shfl_up(incl, off);
            if (lane >= off) incl += t;
        }
        if (lane == 63) ws[w] = incl;
        __syncthreads();
        int wpre = 0;
        for (int k = 0; k < w; ++k) wpre += ws[k];
        int carry = s_carry;
        if (idx < nb) partial[idx] = carry + wpre + incl - v;
        __syncthreads();
        if (tid == 255) s_carry = carry + wpre + incl;
        __syncthreads();
    }
}

__global__ __launch_bounds__(256) void scan_p3g(const int* __restrict__ in,
                                                const int* __restrict__ partial,
                                                int* __restrict__ out, int n) {
    __shared__ int ws[4];
    int tid = threadIdx.x, lane = tid & 63, w = tid >> 6;
    int idx = blockIdx.x * 256 + tid;
    int v = (idx < n) ? in[idx] : 0;
    int incl = v;
#pragma unroll
    for (int off = 1; off < 64; off <<= 1) {
        int t = __shfl_up(incl, off);
        if (lane >= off) incl += t;
    }
    if (lane == 63) ws[w] = incl;
    __syncthreads();
    int wpre = 0;
    for (int k = 0; k < w; ++k) wpre += ws[k];
    if (idx < n) out[idx] = partial[blockIdx.x] + wpre + incl - v;
    if (idx == n - 1) out[n] = partial[blockIdx.x] + wpre + incl;
}

__global__ __launch_bounds__(256) void k3_scatter(const int* __restrict__ ei, int E, int Et,
                                                  const int* __restrict__ g_scan,
                                                  uint2* __restrict__ tmp, int NB) {
    __shared__ int hist[256], lofs[256], lcnt[256], gbase[256];
    __shared__ int ws4[4];
    __shared__ uint2 stage[4096];
    int tid = threadIdx.x, b = blockIdx.x;
    int lane = tid & 63, w = tid >> 6;
    int base = b * 4096;
    int valid = min(4096, Et - base);
    uint2 ev[16];
    hist[tid] = 0;
    lcnt[tid] = 0;
    gbase[tid] = g_scan[tid * NB + b];
    __syncthreads();
#pragma unroll
    for (int k = 0; k < 16; ++k) {
        int e = base + k * 256 + tid;
        if (e < Et) {
            int s, d;
            if (e < E) { s = ei[e]; d = ei[E + e]; } else { s = d = e - E; }
            ev[k] = make_uint2((unsigned)d, (unsigned)s);
            atomicAdd(&hist[d >> 8], 1);
        }
    }
    __syncthreads();
    // exclusive scan of hist -> lofs
    {
        int v = hist[tid];
        int incl = v;
#pragma unroll
        for (int off = 1; off < 64; off <<= 1) {
            int t = __shfl_up(incl, off);
            if (lane >= off) incl += t;
        }
        if (lane == 63) ws4[w] = incl;
        __syncthreads();
        int wpre = 0;
        for (int k = 0; k < w; ++k) wpre += ws4[k];
        lofs[tid] = wpre + incl - v;
    }
    __syncthreads();
#pragma unroll
    for (int k = 0; k < 16; ++k) {
        int e = base + k * 256 + tid;
        if (e < Et) {
            int dg = ev[k].x >> 8;
            int r = atomicAdd(&lcnt[dg], 1);
            stage[lofs[dg] + r] = ev[k];
        }
    }
    __syncthreads();
    for (int j = tid; j < valid; j += 256) {
        uint2 v = stage[j];
        int dg = v.x >> 8;
        tmp[gbase[dg] + (j - lofs[dg])] = v;
    }
}

__global__ __launch_bounds__(256) void csr_finalize(const uint2* __restrict__ tmp,
                                                    const int* __restrict__ g_scan,
                                                    int* __restrict__ srcs,
                                                    int* __restrict__ rowptr,
                                                    int N, int Et, int NB) {
    __shared__ int cnt[256], lofs[256], lcnt[256];
    __shared__ int ws4[4];
    int tid = threadIdx.x, g = blockIdx.x;
    int lane = tid & 63, w = tid >> 6;
    int start = g_scan[g * NB];
    int end = g_scan[(g + 1) * NB];
    cnt[tid] = 0;
    lcnt[tid] = 0;
    __syncthreads();
    for (int e = start + tid; e < end; e += 256)
        atomicAdd(&cnt[tmp[e].x & 255u], 1);
    __syncthreads();
    {
        int v = cnt[tid];
        int incl = v;
#pragma unroll
        for (int off = 1; off < 64; off <<= 1) {
            int t = __shfl_up(incl, off);
            if (lane >= off) incl += t;
        }
        if (lane == 63) ws4[w] = incl;
        __syncthreads();
        int wpre = 0;
        for (int k = 0; k < w; ++k) wpre += ws4[k];
        lofs[tid] = wpre + incl - v;
    }
    __syncthreads();
    int d = g * 256 + tid;
    if (d < N) rowptr[d] = start + lofs[tid];
    if (d == N - 1) rowptr[N] = Et;
    for (int e = start + tid; e < end; e += 256) {
        uint2 v = tmp[e];
        int sub = v.x & 255u;
        int pos = start + lofs[sub] + atomicAdd(&lcnt[sub], 1);
        srcs[pos] = (int)v.y;
    }
}

// ---------------- MFMA GEMM (bf16 out) + fused node_alpha, 16 rows/wave ----------------
template<int M, int H>
__global__ __launch_bounds__(256) void gemm_mfma(const unsigned short* __restrict__ Ab,
                                                 const unsigned short* __restrict__ Wb,
                                                 const float* __restrict__ att_s,
                                                 const float* __restrict__ att_d,
                                                 unsigned short* __restrict__ Cb,
                                                 float* __restrict__ as_,
                                                 float* __restrict__ ad_,
                                                 int N) {
    constexpr int CT = M / 16;
    int tid = threadIdx.x;
    int wid = tid >> 6, l = tid & 63;
    int l15 = l & 15, lhi = l >> 4;
    int rowbase = blockIdx.x * 64 + wid * 16;
    f32x4 acc[CT] = {};

    int rc = min(rowbase + l15, N - 1);
    const unsigned short* ap = Ab + (size_t)rc * 128 + lhi * 8;
    const unsigned short* wp = Wb + (size_t)l15 * 128 + lhi * 8;

#pragma unroll
    for (int ks = 0; ks < 4; ++ks) {
        int k0 = ks * 32;
        bf16x8 a = *reinterpret_cast<const bf16x8*>(ap + k0);
#pragma unroll
        for (int ct = 0; ct < CT; ++ct) {
            bf16x8 b = *reinterpret_cast<const bf16x8*>(wp + (size_t)ct * 16 * 128 + k0);
            acc[ct] = __builtin_amdgcn_mfma_f32_16x16x32_bf16(a, b, acc[ct], 0, 0, 0);
        }
    }

    int rbase = rowbase + lhi * 4;
#pragma unroll
    for (int j = 0; j < 4; ++j) {
        int gr = rbase + j;
        if (gr < N) {
#pragma unroll
            for (int ct = 0; ct < CT; ++ct)
                Cb[(size_t)gr * M + ct * 16 + l15] = f2bf(acc[ct][j]);
        }
    }
#pragma unroll
    for (int hd = 0; hd < H; ++hd) {
        float ps0 = 0.f, ps1 = 0.f, ps2 = 0.f, ps3 = 0.f;
        float pd0 = 0.f, pd1 = 0.f, pd2 = 0.f, pd3 = 0.f;
#pragma unroll
        for (int c4 = 0; c4 < 4; ++c4) {
            int ct = hd * 4 + c4;
            float ws = att_s[hd * 64 + c4 * 16 + l15];
            float wd = att_d[hd * 64 + c4 * 16 + l15];
            ps0 += acc[ct][0] * ws; pd0 += acc[ct][0] * wd;
            ps1 += acc[ct][1] * ws; pd1 += acc[ct][1] * wd;
            ps2 += acc[ct][2] * ws; pd2 += acc[ct][2] * wd;
            ps3 += acc[ct][3] * ws; pd3 += acc[ct][3] * wd;
        }
#pragma unroll
        for (int o = 1; o < 16; o <<= 1) {
            ps0 += __shfl_xor(ps0, o); pd0 += __shfl_xor(pd0, o);
            ps1 += __shfl_xor(ps1, o); pd1 += __shfl_xor(pd1, o);
            ps2 += __shfl_xor(ps2, o); pd2 += __shfl_xor(pd2, o);
            ps3 += __shfl_xor(ps3, o); pd3 += __shfl_xor(pd3, o);
        }
        if (l15 == 0) {
            int gr = rbase;
            if (gr < N)     { as_[(size_t)gr * H + hd] = ps0; ad_[(size_t)gr * H + hd] = pd0; }
            if (gr + 1 < N) { as_[(size_t)(gr + 1) * H + hd] = ps1; ad_[(size_t)(gr + 1) * H + hd] = pd1; }
            if (gr + 2 < N) { as_[(size_t)(gr + 2) * H + hd] = ps2; ad_[(size_t)(gr + 2) * H + hd] = pd2; }
            if (gr + 3 < N) { as_[(size_t)(gr + 3) * H + hd] = ps3; ad_[(size_t)(gr + 3) * H + hd] = pd3; }
        }
    }
}

// ---------------- fused softmax + aggregation (bf16 features, LDS-staged alpha) --------
template<int H, bool DO_ELU>
__global__ __launch_bounds__(256) void gat_agg(const int* __restrict__ rowptr,
                                               const int* __restrict__ srcs,
                                               const float* __restrict__ as_,
                                               const float* __restrict__ ad_,
                                               const unsigned* __restrict__ hfeat,
                                               const float* __restrict__ bias,
                                               void* __restrict__ outp, int N) {
    constexpr int RW = 32 * H;            // u32 words per feature row
    constexpr int G  = (H == 2) ? 4 : 8;  // edges per iteration
    constexpr int GL = 64 / G;            // lanes per edge
    __shared__ uint2 sent[4][72];
    int wid = threadIdx.x >> 6, lane = threadIdx.x & 63;
    int il = lane & (GL - 1);
    int grp = lane >> ((H == 2) ? 4 : 3);
    int d = blockIdx.x * 4 + wid;
    if (d >= N) return;
    if (lane < 8) sent[wid][64 + lane] = make_uint2(0u, 0u);
    int r0 = rowptr[d], r1 = rowptr[d + 1];
    int cnt = r1 - r0;
    float uad[H];
#pragma unroll
    for (int h = 0; h < H; ++h) uad[h] = ad_[(size_t)d * H + h];
    float a0 = 0.f, a1 = 0.f, a2 = 0.f, a3 = 0.f, a4 = 0.f, a5 = 0.f, a6 = 0.f, a7 = 0.f;
    const unsigned* hfl = hfeat + 4 * il;     // lane-fixed word offset
    bool hhi = (H == 2) && (il >= 8);         // which head this lane's channels belong to

    if (cnt <= 64) {
        int i = r0 + lane;
        bool act = i < r1;
        int se = act ? srcs[i] : 0;
        float ax[H];
#pragma unroll
        for (int h = 0; h < H; ++h) {
            float sc = act ? lrelu(as_[(size_t)se * H + h] + uad[h]) : -3.4e38f;
            float m = wred_max(sc);
            float ex = act ? expf(sc - m) : 0.f;
            float den = wred_sum(ex);
            ax[h] = ex / (den + 1e-16f);
        }
        unsigned pk = (H == 2) ? pkf16(ax[0], ax[H - 1]) : __float_as_uint(ax[0]);
        sent[wid][lane] = make_uint2((unsigned)(se * RW), pk);
        __threadfence_block();
#pragma unroll 2
        for (int t = 0; t < cnt; t += G) {
            uint2 en = sent[wid][t + grp];
            float af = (H == 2)
                ? f16b2f((unsigned short)(hhi ? (en.y >> 16) : (en.y & 0xffffu)))
                : __uint_as_float(en.y);
            uint4 u = *(const uint4*)(hfl + en.x);
            a0 += af * bf16lo(u.x); a1 += af * bf16hi(u.x);
            a2 += af * bf16lo(u.y); a3 += af * bf16hi(u.y);
            a4 += af * bf16lo(u.z); a5 += af * bf16hi(u.z);
            a6 += af * bf16lo(u.w); a7 += af * bf16hi(u.w);
        }
    } else {
        // generic chunked path (deg > 64) -- statistically never, correctness only
        float mx[H];
#pragma unroll
        for (int h = 0; h < H; ++h) mx[h] = -3.4e38f;
        for (int base = r0; base < r1; base += 64) {
            int i = base + lane;
            bool act = i < r1;
            int s = act ? srcs[i] : 0;
#pragma unroll
            for (int h = 0; h < H; ++h) {
                float sc = act ? lrelu(as_[(size_t)s * H + h] + uad[h]) : -3.4e38f;
                mx[h] = fmaxf(mx[h], sc);
            }
        }
#pragma unroll
        for (int h = 0; h < H; ++h) mx[h] = wred_max(mx[h]);
        float den[H] = {};
        for (int base = r0; base < r1; base += 64) {
            int i = base + lane;
            bool act = i < r1;
            int s = act ? srcs[i] : 0;
#pragma unroll
            for (int h = 0; h < H; ++h)
                den[h] += act ? expf(lrelu(as_[(size_t)s * H + h] + uad[h]) - mx[h]) : 0.f;
        }
        float inv[H];
#pragma unroll
        for (int h = 0; h < H; ++h) inv[h] = 1.f / (wred_sum(den[h]) + 1e-16f);
        for (int base = r0; base < r1; base += 64) {
            int i = base + lane;
            bool act = i < r1;
            int se = act ? srcs[i] : 0;
            float ax[H];
#pragma unroll
            for (int h = 0; h < H; ++h)
                ax[h] = act ? expf(lrelu(as_[(size_t)se * H + h] + uad[h]) - mx[h]) * inv[h] : 0.f;
            int cntc = min(64, r1 - base);
            unsigned pk = (H == 2) ? pkf16(ax[0], ax[H - 1]) : __float_as_uint(ax[0]);
            sent[wid][lane] = make_uint2((unsigned)(se * RW), pk);
            __threadfence_block();
            for (int t = 0; t < cntc; t += G) {
                uint2 en = sent[wid][t + grp];
                float af = (H == 2)
                    ? f16b2f((unsigned short)(hhi ? (en.y >> 16) : (en.y & 0xffffu)))
                    : __uint_as_float(en.y);
                uint4 u = *(const uint4*)(hfl + en.x);
                a0 += af * bf16lo(u.x); a1 += af * bf16hi(u.x);
                a2 += af * bf16lo(u.y); a3 += af * bf16hi(u.y);
                a4 += af * bf16lo(u.z); a5 += af * bf16hi(u.z);
                a6 += af * bf16lo(u.w); a7 += af * bf16hi(u.w);
            }
            __threadfence_block();
        }
    }

    // cross-group reduction
#pragma unroll
    for (int o = GL; o < 64; o <<= 1) {
        a0 += __shfl_xor(a0, o); a1 += __shfl_xor(a1, o);
        a2 += __shfl_xor(a2, o); a3 += __shfl_xor(a3, o);
        a4 += __shfl_xor(a4, o); a5 += __shfl_xor(a5, o);
        a6 += __shfl_xor(a6, o); a7 += __shfl_xor(a7, o);
    }
    if (grp == 0) {
        int c0 = 8 * il;
        float4 bA = *(const float4*)(bias + c0);
        float4 bB = *(const float4*)(bias + c0 + 4);
        float v0 = a0 + bA.x, v1 = a1 + bA.y, v2 = a2 + bA.z, v3 = a3 + bA.w;
        float v4 = a4 + bB.x, v5 = a5 + bB.y, v6 = a6 + bB.z, v7 = a7 + bB.w;
        if (DO_ELU) {
            v0 = v0 > 0.f ? v0 : expm1f(v0); v1 = v1 > 0.f ? v1 : expm1f(v1);
            v2 = v2 > 0.f ? v2 : expm1f(v2); v3 = v3 > 0.f ? v3 : expm1f(v3);
            v4 = v4 > 0.f ? v4 : expm1f(v4); v5 = v5 > 0.f ? v5 : expm1f(v5);
            v6 = v6 > 0.f ? v6 : expm1f(v6); v7 = v7 > 0.f ? v7 : expm1f(v7);
        }
        if (H == 2) {
            uint4 o;
            o.x = pkbf(v0, v1); o.y = pkbf(v2, v3);
            o.z = pkbf(v4, v5); o.w = pkbf(v6, v7);
            *(uint4*)((unsigned*)outp + (size_t)d * 64 + 4 * il) = o;
        } else {
            *(float4*)((float*)outp + (size_t)d * 64 + c0) = make_float4(v0, v1, v2, v3);
            *(float4*)((float*)outp + (size_t)d * 64 + c0 + 4) = make_float4(v4, v5, v6, v7);
        }
    }
}

extern "C" void kernel_launch(void* const* d_in, const int* in_sizes, int n_in,
                              void* d_out, int out_size, void* d_ws, size_t ws_size,
                              hipStream_t stream) {
    const float* x   = (const float*)d_in[0];
    const int*   ei  = (const int*)d_in[1];
    const float* W1  = (const float*)d_in[2];
    const float* a1s = (const float*)d_in[3];
    const float* a1d = (const float*)d_in[4];
    const float* b1  = (const float*)d_in[5];
    const float* W2  = (const float*)d_in[6];
    const float* a2s = (const float*)d_in[7];
    const float* a2d = (const float*)d_in[8];
    const float* b2  = (const float*)d_in[9];
    float* out = (float*)d_out;

    int N  = in_sizes[0] / 128;
    int E  = in_sizes[1] / 2;
    int Et = E + N;
    int NB = (Et + 4095) / 4096;           // phase-1 blocks
    int nh = 256 * NB;                      // histogram entries

    char* p = (char*)d_ws;
    unsigned short* xb = (unsigned short*)p;    p += (size_t)N * 128 * 2;
    unsigned short* h1b = (unsigned short*)p;   p += (size_t)N * 128 * 2;
    unsigned short* act1b = (unsigned short*)p; p += (size_t)N * 128 * 2;
    unsigned short* w1b = (unsigned short*)p;   p += 128 * 128 * 2;
    unsigned short* w2b = (unsigned short*)p;   p += 64 * 128 * 2;
    uint2* tmp = (uint2*)p;                p += (size_t)Et * 8;
    int* g_hist = (int*)p;                 p += (size_t)nh * 4;
    int* g_scan = (int*)p;                 p += (size_t)(nh + 1) * 4;
    int* partial = (int*)p;                p += (size_t)((nh + 255) / 256) * 4;
    float* as1 = (float*)p;                p += (size_t)N * 2 * 4;
    float* ad1 = (float*)p;                p += (size_t)N * 2 * 4;
    float* as2 = (float*)p;                p += (size_t)N * 4;
    float* ad2 = (float*)p;                p += (size_t)N * 4;
    int* rowptr = (int*)p;                 p += (size_t)(N + 1) * 4;
    int* srcs = (int*)p;                   p += (size_t)Et * 4;
    unsigned short* h2b = xb;              // alias: xb dead after gemm1

    // ---- CSR build: no global atomics ----
    int nbs = (nh + 255) / 256;
    k1_hist<<<NB, 256, 0, stream>>>(ei, E, Et, g_hist, NB);
    scan_p1<<<nbs, 256, 0, stream>>>(g_hist, partial, nh);
    scan_p2<<<1, 256, 0, stream>>>(partial, nbs);
    scan_p3g<<<nbs, 256, 0, stream>>>(g_hist, partial, g_scan, nh);
    k3_scatter<<<NB, 256, 0, stream>>>(ei, E, Et, g_scan, tmp, NB);
    csr_finalize<<<256, 256, 0, stream>>>(tmp, g_scan, srcs, rowptr, N, Et, NB);

    // ---- casts ----
    cast_bf16<<<((size_t)N * 128 / 8 + 255) / 256, 256, 0, stream>>>(x, xb, (size_t)N * 128);
    cast_bf16<<<(128 * 128 / 8 + 255) / 256, 256, 0, stream>>>(W1, w1b, 128 * 128);
    cast_bf16<<<(64 * 128 / 8 + 255) / 256, 256, 0, stream>>>(W2, w2b, 64 * 128);

    // ---- layer 1 ----
    gemm_mfma<128, 2><<<(N + 63) / 64, 256, 0, stream>>>(xb, w1b, a1s, a1d, h1b, as1, ad1, N);
    gat_agg<2, true><<<(N + 3) / 4, 256, 0, stream>>>(rowptr, srcs, as1, ad1,
                                                      (const unsigned*)h1b, b1, act1b, N);

    // ---- layer 2 ----
    gemm_mfma<64, 1><<<(N + 63) / 64, 256, 0, stream>>>(act1b, w2b, a2s, a2d, h2b, as2, ad2, N);
    gat_agg<1, false><<<(N + 3) / 4, 256, 0, stream>>>(rowptr, srcs, as2, ad2,
                                                       (const unsigned*)h2b, b2, out, N);
}

// Round 10
// 149.607 us; speedup vs baseline: 7.8601x; 1.0637x over previous
//
#include <hip/hip_runtime.h>
#include <hip/hip_bf16.h>
#include <math.h>

typedef __bf16 bf16x8 __attribute__((ext_vector_type(8)));
typedef float f32x4 __attribute__((ext_vector_type(4)));
typedef float f32x2 __attribute__((ext_vector_type(2)));

__device__ __forceinline__ float lrelu(float x) { return x > 0.f ? x : 0.2f * x; }
__device__ __forceinline__ unsigned short f2bf(float f) {
    unsigned u = __float_as_uint(f);
    return (unsigned short)((u + 0x7fffu + ((u >> 16) & 1u)) >> 16);
}
__device__ __forceinline__ float bf16lo(unsigned u) { return __uint_as_float(u << 16); }
__device__ __forceinline__ float bf16hi(unsigned u) { return __uint_as_float(u & 0xffff0000u); }
__device__ __forceinline__ unsigned pkbf(float a, float b) {
    return (unsigned)f2bf(a) | ((unsigned)f2bf(b) << 16);
}
__device__ __forceinline__ float wred_sum(float v) {
#pragma unroll
    for (int o = 32; o; o >>= 1) v += __shfl_xor(v, o);
    return v;
}

// ---------------- f32 -> bf16 cast (n % 8 == 0) ----------------
__global__ __launch_bounds__(256) void cast_bf16(const float* __restrict__ in,
                                                 unsigned short* __restrict__ out, size_t n) {
    size_t i = ((size_t)blockIdx.x * 256 + threadIdx.x) * 8;
    if (i >= n) return;
    float4 v0 = *(const float4*)(in + i);
    float4 v1 = *(const float4*)(in + i + 4);
    union { unsigned short u[8]; uint4 q; } o;
    o.u[0] = f2bf(v0.x); o.u[1] = f2bf(v0.y); o.u[2] = f2bf(v0.z); o.u[3] = f2bf(v0.w);
    o.u[4] = f2bf(v1.x); o.u[5] = f2bf(v1.y); o.u[6] = f2bf(v1.z); o.u[7] = f2bf(v1.w);
    *(uint4*)(out + i) = o.q;
}

// ================= CSR build: two-level bucket sort, no global atomics =================
__global__ __launch_bounds__(256) void k1_hist(const int* __restrict__ ei, int E, int Et,
                                               int* __restrict__ g_hist, int NB) {
    __shared__ int hist[256];
    int tid = threadIdx.x, b = blockIdx.x;
    hist[tid] = 0;
    __syncthreads();
    int base = b * 4096;
#pragma unroll
    for (int k = 0; k < 16; ++k) {
        int e = base + k * 256 + tid;
        if (e < Et) {
            int d = (e < E) ? ei[E + e] : (e - E);
            atomicAdd(&hist[d >> 8], 1);
        }
    }
    __syncthreads();
    g_hist[tid * NB + b] = hist[tid];
}

__global__ __launch_bounds__(256) void scan_p1(const int* __restrict__ in,
                                               int* __restrict__ partial, int n) {
    __shared__ int ws[4];
    int tid = threadIdx.x, lane = tid & 63, w = tid >> 6;
    int idx = blockIdx.x * 256 + tid;
    int v = (idx < n) ? in[idx] : 0;
    int s = v;
#pragma unroll
    for (int o = 32; o; o >>= 1) s += __shfl_xor(s, o);
    if (lane == 0) ws[w] = s;
    __syncthreads();
    if (tid == 0) partial[blockIdx.x] = ws[0] + ws[1] + ws[2] + ws[3];
}

__global__ __launch_bounds__(256) void scan_p2(int* __restrict__ partial, int nb) {
    __shared__ int ws[4];
    __shared__ int s_carry;
    int tid = threadIdx.x, lane = tid & 63, w = tid >> 6;
    if (tid == 0) s_carry = 0;
    __syncthreads();
    for (int base = 0; base < nb; base += 256) {
        int idx = base + tid;
        int v = (idx < nb) ? partial[idx] : 0;
        int incl = v;
#pragma unroll
        for (int off = 1; off < 64; off <<= 1) {
            int t = __shfl_up(incl, off);
            if (lane >= off) incl += t;
        }
        if (lane == 63) ws[w] = incl;
        __syncthreads();
        int wpre = 0;
        for (int k = 0; k < w; ++k) wpre += ws[k];
        int carry = s_carry;
        if (idx < nb) partial[idx] = carry + wpre + incl - v;
        __syncthreads();
        if (tid == 255) s_carry = carry + wpre + incl;
        __syncthreads();
    }
}

__global__ __launch_bounds__(256) void scan_p3g(const int* __restrict__ in,
                                                const int* __restrict__ partial,
                                                int* __restrict__ out, int n) {
    __shared__ int ws[4];
    int tid = threadIdx.x, lane = tid & 63, w = tid >> 6;
    int idx = blockIdx.x * 256 + tid;
    int v = (idx < n) ? in[idx] : 0;
    int incl = v;
#pragma unroll
    for (int off = 1; off < 64; off <<= 1) {
        int t = __shfl_up(incl, off);
        if (lane >= off) incl += t;
    }
    if (lane == 63) ws[w] = incl;
    __syncthreads();
    int wpre = 0;
    for (int k = 0; k < w; ++k) wpre += ws[k];
    if (idx < n) out[idx] = partial[blockIdx.x] + wpre + incl - v;
    if (idx == n - 1) out[n] = partial[blockIdx.x] + wpre + incl;
}

__global__ __launch_bounds__(256) void k3_scatter(const int* __restrict__ ei, int E, int Et,
                                                  const int* __restrict__ g_scan,
                                                  uint2* __restrict__ tmp, int NB) {
    __shared__ int hist[256], lofs[256], lcnt[256], gbase[256];
    __shared__ int ws4[4];
    __shared__ uint2 stage[4096];
    int tid = threadIdx.x, b = blockIdx.x;
    int lane = tid & 63, w = tid >> 6;
    int base = b * 4096;
    int valid = min(4096, Et - base);
    uint2 ev[16];
    hist[tid] = 0;
    lcnt[tid] = 0;
    gbase[tid] = g_scan[tid * NB + b];
    __syncthreads();
#pragma unroll
    for (int k = 0; k < 16; ++k) {
        int e = base + k * 256 + tid;
        if (e < Et) {
            int s, d;
            if (e < E) { s = ei[e]; d = ei[E + e]; } else { s = d = e - E; }
            ev[k] = make_uint2((unsigned)d, (unsigned)s);
            atomicAdd(&hist[d >> 8], 1);
        }
    }
    __syncthreads();
    {
        int v = hist[tid];
        int incl = v;
#pragma unroll
        for (int off = 1; off < 64; off <<= 1) {
            int t = __shfl_up(incl, off);
            if (lane >= off) incl += t;
        }
        if (lane == 63) ws4[w] = incl;
        __syncthreads();
        int wpre = 0;
        for (int k = 0; k < w; ++k) wpre += ws4[k];
        lofs[tid] = wpre + incl - v;
    }
    __syncthreads();
#pragma unroll
    for (int k = 0; k < 16; ++k) {
        int e = base + k * 256 + tid;
        if (e < Et) {
            int dg = ev[k].x >> 8;
            int r = atomicAdd(&lcnt[dg], 1);
            stage[lofs[dg] + r] = ev[k];
        }
    }
    __syncthreads();
    for (int j = tid; j < valid; j += 256) {
        uint2 v = stage[j];
        int dg = v.x >> 8;
        tmp[gbase[dg] + (j - lofs[dg])] = v;
    }
}

__global__ __launch_bounds__(256) void csr_finalize(const uint2* __restrict__ tmp,
                                                    const int* __restrict__ g_scan,
                                                    int* __restrict__ srcs,
                                                    int* __restrict__ rowptr,
                                                    int N, int Et, int NB) {
    __shared__ int cnt[256], lofs[256], lcnt[256];
    __shared__ int ws4[4];
    int tid = threadIdx.x, g = blockIdx.x;
    int lane = tid & 63, w = tid >> 6;
    int start = g_scan[g * NB];
    int end = g_scan[(g + 1) * NB];
    cnt[tid] = 0;
    lcnt[tid] = 0;
    __syncthreads();
    for (int e = start + tid; e < end; e += 256)
        atomicAdd(&cnt[tmp[e].x & 255u], 1);
    __syncthreads();
    {
        int v = cnt[tid];
        int incl = v;
#pragma unroll
        for (int off = 1; off < 64; off <<= 1) {
            int t = __shfl_up(incl, off);
            if (lane >= off) incl += t;
        }
        if (lane == 63) ws4[w] = incl;
        __syncthreads();
        int wpre = 0;
        for (int k = 0; k < w; ++k) wpre += ws4[k];
        lofs[tid] = wpre + incl - v;
    }
    __syncthreads();
    int d = g * 256 + tid;
    if (d < N) rowptr[d] = start + lofs[tid];
    if (d == N - 1) rowptr[N] = Et;
    for (int e = start + tid; e < end; e += 256) {
        uint2 v = tmp[e];
        int sub = v.x & 255u;
        int pos = start + lofs[sub] + atomicAdd(&lcnt[sub], 1);
        srcs[pos] = (int)v.y;
    }
}

// ---------------- MFMA GEMM (bf16 out) + fused node_alpha, 16 rows/wave ----------------
template<int M, int H>
__global__ __launch_bounds__(256) void gemm_mfma(const unsigned short* __restrict__ Ab,
                                                 const unsigned short* __restrict__ Wb,
                                                 const float* __restrict__ att_s,
                                                 const float* __restrict__ att_d,
                                                 unsigned short* __restrict__ Cb,
                                                 float* __restrict__ as_,
                                                 float* __restrict__ ad_,
                                                 int N) {
    constexpr int CT = M / 16;
    int tid = threadIdx.x;
    int wid = tid >> 6, l = tid & 63;
    int l15 = l & 15, lhi = l >> 4;
    int rowbase = blockIdx.x * 64 + wid * 16;
    f32x4 acc[CT] = {};

    int rc = min(rowbase + l15, N - 1);
    const unsigned short* ap = Ab + (size_t)rc * 128 + lhi * 8;
    const unsigned short* wp = Wb + (size_t)l15 * 128 + lhi * 8;

#pragma unroll
    for (int ks = 0; ks < 4; ++ks) {
        int k0 = ks * 32;
        bf16x8 a = *reinterpret_cast<const bf16x8*>(ap + k0);
#pragma unroll
        for (int ct = 0; ct < CT; ++ct) {
            bf16x8 b = *reinterpret_cast<const bf16x8*>(wp + (size_t)ct * 16 * 128 + k0);
            acc[ct] = __builtin_amdgcn_mfma_f32_16x16x32_bf16(a, b, acc[ct], 0, 0, 0);
        }
    }

    int rbase = rowbase + lhi * 4;
#pragma unroll
    for (int j = 0; j < 4; ++j) {
        int gr = rbase + j;
        if (gr < N) {
#pragma unroll
            for (int ct = 0; ct < CT; ++ct)
                Cb[(size_t)gr * M + ct * 16 + l15] = f2bf(acc[ct][j]);
        }
    }
#pragma unroll
    for (int hd = 0; hd < H; ++hd) {
        float ps0 = 0.f, ps1 = 0.f, ps2 = 0.f, ps3 = 0.f;
        float pd0 = 0.f, pd1 = 0.f, pd2 = 0.f, pd3 = 0.f;
#pragma unroll
        for (int c4 = 0; c4 < 4; ++c4) {
            int ct = hd * 4 + c4;
            float ws = att_s[hd * 64 + c4 * 16 + l15];
            float wd = att_d[hd * 64 + c4 * 16 + l15];
            ps0 += acc[ct][0] * ws; pd0 += acc[ct][0] * wd;
            ps1 += acc[ct][1] * ws; pd1 += acc[ct][1] * wd;
            ps2 += acc[ct][2] * ws; pd2 += acc[ct][2] * wd;
            ps3 += acc[ct][3] * ws; pd3 += acc[ct][3] * wd;
        }
#pragma unroll
        for (int o = 1; o < 16; o <<= 1) {
            ps0 += __shfl_xor(ps0, o); pd0 += __shfl_xor(pd0, o);
            ps1 += __shfl_xor(ps1, o); pd1 += __shfl_xor(pd1, o);
            ps2 += __shfl_xor(ps2, o); pd2 += __shfl_xor(pd2, o);
            ps3 += __shfl_xor(ps3, o); pd3 += __shfl_xor(pd3, o);
        }
        if (l15 == 0) {
            int gr = rbase;
            if (gr < N)     { as_[(size_t)gr * H + hd] = ps0; ad_[(size_t)gr * H + hd] = pd0; }
            if (gr + 1 < N) { as_[(size_t)(gr + 1) * H + hd] = ps1; ad_[(size_t)(gr + 1) * H + hd] = pd1; }
            if (gr + 2 < N) { as_[(size_t)(gr + 2) * H + hd] = ps2; ad_[(size_t)(gr + 2) * H + hd] = pd2; }
            if (gr + 3 < N) { as_[(size_t)(gr + 3) * H + hd] = ps3; ad_[(size_t)(gr + 3) * H + hd] = pd3; }
        }
    }
}

// ------- fused softmax + aggregation (no-max softmax, f32 alpha in LDS, pk-fma core) ---
// LDS entry (16B): {byte_off, alpha0, byte_off, alpha_{H-1}} -> lane ds_read_b64 at +8*head.
// H=2: 16 lanes/edge, 4 edges/iter, uint4 loads (8 ch/lane), bf16 out.
// H=1: 8 lanes/edge, 8 edges/iter, uint4 loads (8 ch/lane), f32 out.
template<int H, bool DO_ELU>
__global__ __launch_bounds__(256) void gat_agg(const int* __restrict__ rowptr,
                                               const int* __restrict__ srcs,
                                               const float* __restrict__ as_,
                                               const float* __restrict__ ad_,
                                               const unsigned* __restrict__ hfeat,
                                               const float* __restrict__ bias,
                                               void* __restrict__ outp, int N) {
    constexpr int RW = 32 * H;            // u32 words per feature row
    constexpr int G  = (H == 2) ? 4 : 8;  // edges per iteration
    constexpr int GL = 64 / G;            // lanes per edge
    __shared__ uint4 sent[4][64];
    int wid = threadIdx.x >> 6, lane = threadIdx.x & 63;
    int il = lane & (GL - 1);
    int grp = lane >> ((H == 2) ? 4 : 3);
    int d = blockIdx.x * 4 + wid;
    if (d >= N) return;
    int r0 = rowptr[d], r1 = rowptr[d + 1];
    int cnt = r1 - r0;
    float uad[H];
#pragma unroll
    for (int h = 0; h < H; ++h) uad[h] = ad_[(size_t)d * H + h];
    f32x2 A01 = {0.f, 0.f}, A23 = {0.f, 0.f}, A45 = {0.f, 0.f}, A67 = {0.f, 0.f};
    const char* hflb = (const char*)hfeat + 16 * il;   // lane-fixed byte offset
    bool hhi = (H == 2) && (il >= 8);
    const unsigned* sbase = reinterpret_cast<const unsigned*>(&sent[wid][0]) + (hhi ? 2 : 0);

    if (cnt <= 64) {
        int i = r0 + lane;
        bool act = i < r1;
        int se = act ? srcs[i] : 0;
        float ax[H];
#pragma unroll
        for (int h = 0; h < H; ++h) {
            float sc = lrelu(as_[(size_t)se * H + h] + uad[h]);
            float ex = act ? __expf(sc) : 0.f;          // |sc| small: no max needed
            float den = wred_sum(ex);
            ax[h] = ex * __builtin_amdgcn_rcpf(den + 1e-16f);
        }
        unsigned off = (unsigned)(se * (RW * 4));
        sent[wid][lane] = make_uint4(off, __float_as_uint(ax[0]),
                                     off, __float_as_uint(ax[H - 1]));
        __threadfence_block();
#pragma unroll 2
        for (int t = 0; t < cnt; t += G) {
            uint2 en = *(const uint2*)(sbase + 4 * (t + grp));
            float af = __uint_as_float(en.y);
            uint4 u = *(const uint4*)(hflb + en.x);
            f32x2 c;
            c.x = bf16lo(u.x); c.y = bf16hi(u.x); A01 += af * c;
            c.x = bf16lo(u.y); c.y = bf16hi(u.y); A23 += af * c;
            c.x = bf16lo(u.z); c.y = bf16hi(u.z); A45 += af * c;
            c.x = bf16lo(u.w); c.y = bf16hi(u.w); A67 += af * c;
        }
    } else {
        // chunked path (deg > 64) -- statistically never, correctness only
        float psum[H];
#pragma unroll
        for (int h = 0; h < H; ++h) psum[h] = 0.f;
        for (int base = r0; base < r1; base += 64) {
            int i = base + lane;
            bool act = i < r1;
            int s = act ? srcs[i] : 0;
#pragma unroll
            for (int h = 0; h < H; ++h) {
                float sc = lrelu(as_[(size_t)s * H + h] + uad[h]);
                psum[h] += act ? __expf(sc) : 0.f;
            }
        }
        float inv[H];
#pragma unroll
        for (int h = 0; h < H; ++h)
            inv[h] = __builtin_amdgcn_rcpf(wred_sum(psum[h]) + 1e-16f);
        for (int base = r0; base < r1; base += 64) {
            int i = base + lane;
            bool act = i < r1;
            int se = act ? srcs[i] : 0;
            float ax[H];
#pragma unroll
            for (int h = 0; h < H; ++h) {
                float sc = lrelu(as_[(size_t)se * H + h] + uad[h]);
                ax[h] = act ? __expf(sc) * inv[h] : 0.f;
            }
            int cntc = min(64, r1 - base);
            unsigned off = (unsigned)(se * (RW * 4));
            sent[wid][lane] = make_uint4(off, __float_as_uint(ax[0]),
                                         off, __float_as_uint(ax[H - 1]));
            __threadfence_block();
            for (int t = 0; t < cntc; t += G) {
                uint2 en = *(const uint2*)(sbase + 4 * (t + grp));
                float af = __uint_as_float(en.y);
                uint4 u = *(const uint4*)(hflb + en.x);
                f32x2 c;
                c.x = bf16lo(u.x); c.y = bf16hi(u.x); A01 += af * c;
                c.x = bf16lo(u.y); c.y = bf16hi(u.y); A23 += af * c;
                c.x = bf16lo(u.z); c.y = bf16hi(u.z); A45 += af * c;
                c.x = bf16lo(u.w); c.y = bf16hi(u.w); A67 += af * c;
            }
            __threadfence_block();
        }
    }

    // cross-group reduction
#pragma unroll
    for (int o = GL; o < 64; o <<= 1) {
        A01.x += __shfl_xor(A01.x, o); A01.y += __shfl_xor(A01.y, o);
        A23.x += __shfl_xor(A23.x, o); A23.y += __shfl_xor(A23.y, o);
        A45.x += __shfl_xor(A45.x, o); A45.y += __shfl_xor(A45.y, o);
        A67.x += __shfl_xor(A67.x, o); A67.y += __shfl_xor(A67.y, o);
    }
    if (grp == 0) {
        int c0 = 8 * il;
        float4 bA = *(const float4*)(bias + c0);
        float4 bB = *(const float4*)(bias + c0 + 4);
        float v0 = A01.x + bA.x, v1 = A01.y + bA.y, v2 = A23.x + bA.z, v3 = A23.y + bA.w;
        float v4 = A45.x + bB.x, v5 = A45.y + bB.y, v6 = A67.x + bB.z, v7 = A67.y + bB.w;
        if (DO_ELU) {
            v0 = v0 > 0.f ? v0 : expm1f(v0); v1 = v1 > 0.f ? v1 : expm1f(v1);
            v2 = v2 > 0.f ? v2 : expm1f(v2); v3 = v3 > 0.f ? v3 : expm1f(v3);
            v4 = v4 > 0.f ? v4 : expm1f(v4); v5 = v5 > 0.f ? v5 : expm1f(v5);
            v6 = v6 > 0.f ? v6 : expm1f(v6); v7 = v7 > 0.f ? v7 : expm1f(v7);
        }
        if (H == 2) {
            uint4 o;
            o.x = pkbf(v0, v1); o.y = pkbf(v2, v3);
            o.z = pkbf(v4, v5); o.w = pkbf(v6, v7);
            *(uint4*)((unsigned*)outp + (size_t)d * 64 + 4 * il) = o;
        } else {
            *(float4*)((float*)outp + (size_t)d * 64 + c0) = make_float4(v0, v1, v2, v3);
            *(float4*)((float*)outp + (size_t)d * 64 + c0 + 4) = make_float4(v4, v5, v6, v7);
        }
    }
}

extern "C" void kernel_launch(void* const* d_in, const int* in_sizes, int n_in,
                              void* d_out, int out_size, void* d_ws, size_t ws_size,
                              hipStream_t stream) {
    const float* x   = (const float*)d_in[0];
    const int*   ei  = (const int*)d_in[1];
    const float* W1  = (const float*)d_in[2];
    const float* a1s = (const float*)d_in[3];
    const float* a1d = (const float*)d_in[4];
    const float* b1  = (const float*)d_in[5];
    const float* W2  = (const float*)d_in[6];
    const float* a2s = (const float*)d_in[7];
    const float* a2d = (const float*)d_in[8];
    const float* b2  = (const float*)d_in[9];
    float* out = (float*)d_out;

    int N  = in_sizes[0] / 128;
    int E  = in_sizes[1] / 2;
    int Et = E + N;
    int NB = (Et + 4095) / 4096;           // phase-1 blocks
    int nh = 256 * NB;                      // histogram entries

    char* p = (char*)d_ws;
    unsigned short* xb = (unsigned short*)p;    p += (size_t)N * 128 * 2;
    unsigned short* h1b = (unsigned short*)p;   p += (size_t)N * 128 * 2;
    unsigned short* act1b = (unsigned short*)p; p += (size_t)N * 128 * 2;
    unsigned short* w1b = (unsigned short*)p;   p += 128 * 128 * 2;
    unsigned short* w2b = (unsigned short*)p;   p += 64 * 128 * 2;
    uint2* tmp = (uint2*)p;                p += (size_t)Et * 8;
    int* g_hist = (int*)p;                 p += (size_t)nh * 4;
    int* g_scan = (int*)p;                 p += (size_t)(nh + 1) * 4;
    int* partial = (int*)p;                p += (size_t)((nh + 255) / 256) * 4;
    float* as1 = (float*)p;                p += (size_t)N * 2 * 4;
    float* ad1 = (float*)p;                p += (size_t)N * 2 * 4;
    float* as2 = (float*)p;                p += (size_t)N * 4;
    float* ad2 = (float*)p;                p += (size_t)N * 4;
    int* rowptr = (int*)p;                 p += (size_t)(N + 1) * 4;
    int* srcs = (int*)p;                   p += (size_t)Et * 4;
    unsigned short* h2b = xb;              // alias: xb dead after gemm1

    // ---- CSR build: no global atomics ----
    int nbs = (nh + 255) / 256;
    k1_hist<<<NB, 256, 0, stream>>>(ei, E, Et, g_hist, NB);
    scan_p1<<<nbs, 256, 0, stream>>>(g_hist, partial, nh);
    scan_p2<<<1, 256, 0, stream>>>(partial, nbs);
    scan_p3g<<<nbs, 256, 0, stream>>>(g_hist, partial, g_scan, nh);
    k3_scatter<<<NB, 256, 0, stream>>>(ei, E, Et, g_scan, tmp, NB);
    csr_finalize<<<256, 256, 0, stream>>>(tmp, g_scan, srcs, rowptr, N, Et, NB);

    // ---- casts ----
    cast_bf16<<<((size_t)N * 128 / 8 + 255) / 256, 256, 0, stream>>>(x, xb, (size_t)N * 128);
    cast_bf16<<<(128 * 128 / 8 + 255) / 256, 256, 0, stream>>>(W1, w1b, 128 * 128);
    cast_bf16<<<(64 * 128 / 8 + 255) / 256, 256, 0, stream>>>(W2, w2b, 64 * 128);

    // ---- layer 1 ----
    gemm_mfma<128, 2><<<(N + 63) / 64, 256, 0, stream>>>(xb, w1b, a1s, a1d, h1b, as1, ad1, N);
    gat_agg<2, true><<<(N + 3) / 4, 256, 0, stream>>>(rowptr, srcs, as1, ad1,
                                                      (const unsigned*)h1b, b1, act1b, N);

    // ---- layer 2 ----
    gemm_mfma<64, 1><<<(N + 63) / 64, 256, 0, stream>>>(act1b, w2b, a2s, a2d, h2b, as2, ad2, N);
    gat_agg<1, false><<<(N + 3) / 4, 256, 0, stream>>>(rowptr, srcs, as2, ad2,
                                                       (const unsigned*)h2b, b2, out, N);
}

// Round 11
// 143.577 us; speedup vs baseline: 8.1903x; 1.0420x over previous
//
#include <hip/hip_runtime.h>
#include <hip/hip_bf16.h>
#include <math.h>

typedef __bf16 bf16x8 __attribute__((ext_vector_type(8)));
typedef float f32x4 __attribute__((ext_vector_type(4)));
typedef float f32x2 __attribute__((ext_vector_type(2)));

__device__ __forceinline__ float lrelu(float x) { return x > 0.f ? x : 0.2f * x; }
__device__ __forceinline__ unsigned short f2bf(float f) {
    unsigned u = __float_as_uint(f);
    return (unsigned short)((u + 0x7fffu + ((u >> 16) & 1u)) >> 16);
}
__device__ __forceinline__ float bf16lo(unsigned u) { return __uint_as_float(u << 16); }
__device__ __forceinline__ float bf16hi(unsigned u) { return __uint_as_float(u & 0xffff0000u); }
__device__ __forceinline__ unsigned pkbf(float a, float b) {
    return (unsigned)f2bf(a) | ((unsigned)f2bf(b) << 16);
}
__device__ __forceinline__ float wred_sum(float v) {
#pragma unroll
    for (int o = 32; o; o >>= 1) v += __shfl_xor(v, o);
    return v;
}

// ---------------- W1+W2 -> bf16 cast, single launch ----------------
__global__ __launch_bounds__(256) void cast_w(const float* __restrict__ W1,
                                              const float* __restrict__ W2,
                                              unsigned short* __restrict__ w1b,
                                              unsigned short* __restrict__ w2b) {
    int i = blockIdx.x * 256 + threadIdx.x;   // vec8 index
    const float* src;
    unsigned short* dst;
    size_t off;
    if (i < 2048)      { src = W1; dst = w1b; off = (size_t)i * 8; }
    else if (i < 3072) { src = W2; dst = w2b; off = (size_t)(i - 2048) * 8; }
    else return;
    float4 v0 = *(const float4*)(src + off);
    float4 v1 = *(const float4*)(src + off + 4);
    union { unsigned short u[8]; uint4 q; } o;
    o.u[0] = f2bf(v0.x); o.u[1] = f2bf(v0.y); o.u[2] = f2bf(v0.z); o.u[3] = f2bf(v0.w);
    o.u[4] = f2bf(v1.x); o.u[5] = f2bf(v1.y); o.u[6] = f2bf(v1.z); o.u[7] = f2bf(v1.w);
    *(uint4*)(dst + off) = o.q;
}

// ================= CSR build: two-level bucket sort, no global atomics =================
__global__ __launch_bounds__(256) void k1_hist(const int* __restrict__ ei, int E, int Et,
                                               int* __restrict__ g_hist, int NB) {
    __shared__ int hist[256];
    int tid = threadIdx.x, b = blockIdx.x;
    hist[tid] = 0;
    __syncthreads();
    int base = b * 4096;
#pragma unroll
    for (int k = 0; k < 16; ++k) {
        int e = base + k * 256 + tid;
        if (e < Et) {
            int d = (e < E) ? ei[E + e] : (e - E);
            atomicAdd(&hist[d >> 8], 1);
        }
    }
    __syncthreads();
    g_hist[tid * NB + b] = hist[tid];
}

__global__ __launch_bounds__(256) void scan_p1(const int* __restrict__ in,
                                               int* __restrict__ partial, int n) {
    __shared__ int ws[4];
    int tid = threadIdx.x, lane = tid & 63, w = tid >> 6;
    int idx = blockIdx.x * 256 + tid;
    int v = (idx < n) ? in[idx] : 0;
    int s = v;
#pragma unroll
    for (int o = 32; o; o >>= 1) s += __shfl_xor(s, o);
    if (lane == 0) ws[w] = s;
    __syncthreads();
    if (tid == 0) partial[blockIdx.x] = ws[0] + ws[1] + ws[2] + ws[3];
}

__global__ __launch_bounds__(256) void scan_p2(int* __restrict__ partial, int nb) {
    __shared__ int ws[4];
    __shared__ int s_carry;
    int tid = threadIdx.x, lane = tid & 63, w = tid >> 6;
    if (tid == 0) s_carry = 0;
    __syncthreads();
    for (int base = 0; base < nb; base += 256) {
        int idx = base + tid;
        int v = (idx < nb) ? partial[idx] : 0;
        int incl = v;
#pragma unroll
        for (int off = 1; off < 64; off <<= 1) {
            int t = __shfl_up(incl, off);
            if (lane >= off) incl += t;
        }
        if (lane == 63) ws[w] = incl;
        __syncthreads();
        int wpre = 0;
        for (int k = 0; k < w; ++k) wpre += ws[k];
        int carry = s_carry;
        if (idx < nb) partial[idx] = carry + wpre + incl - v;
        __syncthreads();
        if (tid == 255) s_carry = carry + wpre + incl;
        __syncthreads();
    }
}

__global__ __launch_bounds__(256) void scan_p3g(const int* __restrict__ in,
                                                const int* __restrict__ partial,
                                                int* __restrict__ out, int n) {
    __shared__ int ws[4];
    int tid = threadIdx.x, lane = tid & 63, w = tid >> 6;
    int idx = blockIdx.x * 256 + tid;
    int v = (idx < n) ? in[idx] : 0;
    int incl = v;
#pragma unroll
    for (int off = 1; off < 64; off <<= 1) {
        int t = __shfl_up(incl, off);
        if (lane >= off) incl += t;
    }
    if (lane == 63) ws[w] = incl;
    __syncthreads();
    int wpre = 0;
    for (int k = 0; k < w; ++k) wpre += ws[k];
    if (idx < n) out[idx] = partial[blockIdx.x] + wpre + incl - v;
    if (idx == n - 1) out[n] = partial[blockIdx.x] + wpre + incl;
}

__global__ __launch_bounds__(256) void k3_scatter(const int* __restrict__ ei, int E, int Et,
                                                  const int* __restrict__ g_scan,
                                                  uint2* __restrict__ tmp, int NB) {
    __shared__ int hist[256], lofs[256], lcnt[256], gbase[256];
    __shared__ int ws4[4];
    __shared__ uint2 stage[4096];
    int tid = threadIdx.x, b = blockIdx.x;
    int lane = tid & 63, w = tid >> 6;
    int base = b * 4096;
    int valid = min(4096, Et - base);
    uint2 ev[16];
    hist[tid] = 0;
    lcnt[tid] = 0;
    gbase[tid] = g_scan[tid * NB + b];
    __syncthreads();
#pragma unroll
    for (int k = 0; k < 16; ++k) {
        int e = base + k * 256 + tid;
        if (e < Et) {
            int s, d;
            if (e < E) { s = ei[e]; d = ei[E + e]; } else { s = d = e - E; }
            ev[k] = make_uint2((unsigned)d, (unsigned)s);
            atomicAdd(&hist[d >> 8], 1);
        }
    }
    __syncthreads();
    {
        int v = hist[tid];
        int incl = v;
#pragma unroll
        for (int off = 1; off < 64; off <<= 1) {
            int t = __shfl_up(incl, off);
            if (lane >= off) incl += t;
        }
        if (lane == 63) ws4[w] = incl;
        __syncthreads();
        int wpre = 0;
        for (int k = 0; k < w; ++k) wpre += ws4[k];
        lofs[tid] = wpre + incl - v;
    }
    __syncthreads();
#pragma unroll
    for (int k = 0; k < 16; ++k) {
        int e = base + k * 256 + tid;
        if (e < Et) {
            int dg = ev[k].x >> 8;
            int r = atomicAdd(&lcnt[dg], 1);
            stage[lofs[dg] + r] = ev[k];
        }
    }
    __syncthreads();
    for (int j = tid; j < valid; j += 256) {
        uint2 v = stage[j];
        int dg = v.x >> 8;
        tmp[gbase[dg] + (j - lofs[dg])] = v;
    }
}

__global__ __launch_bounds__(256) void csr_finalize(const uint2* __restrict__ tmp,
                                                    const int* __restrict__ g_scan,
                                                    int* __restrict__ srcs,
                                                    int* __restrict__ rowptr,
                                                    int N, int Et, int NB) {
    __shared__ int cnt[256], lofs[256], lcnt[256];
    __shared__ int ws4[4];
    int tid = threadIdx.x, g = blockIdx.x;
    int lane = tid & 63, w = tid >> 6;
    int start = g_scan[g * NB];
    int end = g_scan[(g + 1) * NB];
    cnt[tid] = 0;
    lcnt[tid] = 0;
    __syncthreads();
    for (int e = start + tid; e < end; e += 256)
        atomicAdd(&cnt[tmp[e].x & 255u], 1);
    __syncthreads();
    {
        int v = cnt[tid];
        int incl = v;
#pragma unroll
        for (int off = 1; off < 64; off <<= 1) {
            int t = __shfl_up(incl, off);
            if (lane >= off) incl += t;
        }
        if (lane == 63) ws4[w] = incl;
        __syncthreads();
        int wpre = 0;
        for (int k = 0; k < w; ++k) wpre += ws4[k];
        lofs[tid] = wpre + incl - v;
    }
    __syncthreads();
    int d = g * 256 + tid;
    if (d < N) rowptr[d] = start + lofs[tid];
    if (d == N - 1) rowptr[N] = Et;
    for (int e = start + tid; e < end; e += 256) {
        uint2 v = tmp[e];
        int sub = v.x & 255u;
        int pos = start + lofs[sub] + atomicAdd(&lcnt[sub], 1);
        srcs[pos] = (int)v.y;
    }
}

// ------- MFMA GEMM (bf16 out) + fused node_alpha; AF32 = on-the-fly f32->bf16 A ------
template<int M, int H, bool AF32>
__global__ __launch_bounds__(256) void gemm_mfma(const void* __restrict__ Av,
                                                 const unsigned short* __restrict__ Wb,
                                                 const float* __restrict__ att_s,
                                                 const float* __restrict__ att_d,
                                                 unsigned short* __restrict__ Cb,
                                                 float* __restrict__ as_,
                                                 float* __restrict__ ad_,
                                                 int N) {
    constexpr int CT = M / 16;
    int tid = threadIdx.x;
    int wid = tid >> 6, l = tid & 63;
    int l15 = l & 15, lhi = l >> 4;
    int rowbase = blockIdx.x * 64 + wid * 16;
    f32x4 acc[CT] = {};

    int rc = min(rowbase + l15, N - 1);
    const unsigned short* ap = (const unsigned short*)Av + (size_t)rc * 128 + lhi * 8;
    const float* apf = (const float*)Av + (size_t)rc * 128 + lhi * 8;
    const unsigned short* wp = Wb + (size_t)l15 * 128 + lhi * 8;

#pragma unroll
    for (int ks = 0; ks < 4; ++ks) {
        int k0 = ks * 32;
        bf16x8 a;
        if (AF32) {
            float4 u0 = *(const float4*)(apf + k0);
            float4 u1 = *(const float4*)(apf + k0 + 4);
            union { unsigned short s[8]; bf16x8 v; } cc;
            cc.s[0] = f2bf(u0.x); cc.s[1] = f2bf(u0.y); cc.s[2] = f2bf(u0.z); cc.s[3] = f2bf(u0.w);
            cc.s[4] = f2bf(u1.x); cc.s[5] = f2bf(u1.y); cc.s[6] = f2bf(u1.z); cc.s[7] = f2bf(u1.w);
            a = cc.v;
        } else {
            a = *reinterpret_cast<const bf16x8*>(ap + k0);
        }
#pragma unroll
        for (int ct = 0; ct < CT; ++ct) {
            bf16x8 b = *reinterpret_cast<const bf16x8*>(wp + (size_t)ct * 16 * 128 + k0);
            acc[ct] = __builtin_amdgcn_mfma_f32_16x16x32_bf16(a, b, acc[ct], 0, 0, 0);
        }
    }

    int rbase = rowbase + lhi * 4;
#pragma unroll
    for (int j = 0; j < 4; ++j) {
        int gr = rbase + j;
        if (gr < N) {
#pragma unroll
            for (int ct = 0; ct < CT; ++ct)
                Cb[(size_t)gr * M + ct * 16 + l15] = f2bf(acc[ct][j]);
        }
    }
#pragma unroll
    for (int hd = 0; hd < H; ++hd) {
        float ps0 = 0.f, ps1 = 0.f, ps2 = 0.f, ps3 = 0.f;
        float pd0 = 0.f, pd1 = 0.f, pd2 = 0.f, pd3 = 0.f;
#pragma unroll
        for (int c4 = 0; c4 < 4; ++c4) {
            int ct = hd * 4 + c4;
            float ws = att_s[hd * 64 + c4 * 16 + l15];
            float wd = att_d[hd * 64 + c4 * 16 + l15];
            ps0 += acc[ct][0] * ws; pd0 += acc[ct][0] * wd;
            ps1 += acc[ct][1] * ws; pd1 += acc[ct][1] * wd;
            ps2 += acc[ct][2] * ws; pd2 += acc[ct][2] * wd;
            ps3 += acc[ct][3] * ws; pd3 += acc[ct][3] * wd;
        }
#pragma unroll
        for (int o = 1; o < 16; o <<= 1) {
            ps0 += __shfl_xor(ps0, o); pd0 += __shfl_xor(pd0, o);
            ps1 += __shfl_xor(ps1, o); pd1 += __shfl_xor(pd1, o);
            ps2 += __shfl_xor(ps2, o); pd2 += __shfl_xor(pd2, o);
            ps3 += __shfl_xor(ps3, o); pd3 += __shfl_xor(pd3, o);
        }
        if (l15 == 0) {
            int gr = rbase;
            if (gr < N)     { as_[(size_t)gr * H + hd] = ps0; ad_[(size_t)gr * H + hd] = pd0; }
            if (gr + 1 < N) { as_[(size_t)(gr + 1) * H + hd] = ps1; ad_[(size_t)(gr + 1) * H + hd] = pd1; }
            if (gr + 2 < N) { as_[(size_t)(gr + 2) * H + hd] = ps2; ad_[(size_t)(gr + 2) * H + hd] = pd2; }
            if (gr + 3 < N) { as_[(size_t)(gr + 3) * H + hd] = ps3; ad_[(size_t)(gr + 3) * H + hd] = pd3; }
        }
    }
}

// ------- fused softmax + aggregation (no-max softmax, f32 alpha in LDS, pk-fma core) ---
template<int H, bool DO_ELU>
__global__ __launch_bounds__(256) void gat_agg(const int* __restrict__ rowptr,
                                               const int* __restrict__ srcs,
                                               const float* __restrict__ as_,
                                               const float* __restrict__ ad_,
                                               const unsigned* __restrict__ hfeat,
                                               const float* __restrict__ bias,
                                               void* __restrict__ outp, int N) {
    constexpr int RW = 32 * H;            // u32 words per feature row
    constexpr int G  = (H == 2) ? 4 : 8;  // edges per iteration
    constexpr int GL = 64 / G;            // lanes per edge
    __shared__ uint4 sent[4][64];
    int wid = threadIdx.x >> 6, lane = threadIdx.x & 63;
    int il = lane & (GL - 1);
    int grp = lane >> ((H == 2) ? 4 : 3);
    int d = blockIdx.x * 4 + wid;
    if (d >= N) return;
    int r0 = rowptr[d], r1 = rowptr[d + 1];
    int cnt = r1 - r0;
    float uad[H];
    if (H == 2) {
        float2 adp = *(const float2*)(ad_ + 2 * (size_t)d);
        uad[0] = adp.x; uad[H - 1] = adp.y;
    } else {
        uad[0] = ad_[d];
    }
    f32x2 A01 = {0.f, 0.f}, A23 = {0.f, 0.f}, A45 = {0.f, 0.f}, A67 = {0.f, 0.f};
    const char* hflb = (const char*)hfeat + 16 * il;   // lane-fixed byte offset
    bool hhi = (H == 2) && (il >= 8);
    const unsigned* sbase = reinterpret_cast<const unsigned*>(&sent[wid][0]) + (hhi ? 2 : 0);

    if (cnt <= 64) {
        int i = r0 + lane;
        bool act = i < r1;
        int se = act ? srcs[i] : 0;
        float ax[H];
        if (H == 2) {
            float2 asp = *(const float2*)(as_ + 2 * (size_t)se);
            float ex0 = act ? __expf(lrelu(asp.x + uad[0])) : 0.f;
            float ex1 = act ? __expf(lrelu(asp.y + uad[1])) : 0.f;
            float den0 = wred_sum(ex0);
            float den1 = wred_sum(ex1);
            ax[0] = ex0 * __builtin_amdgcn_rcpf(den0 + 1e-16f);
            ax[H - 1] = ex1 * __builtin_amdgcn_rcpf(den1 + 1e-16f);
        } else {
            float ex = act ? __expf(lrelu(as_[se] + uad[0])) : 0.f;
            float den = wred_sum(ex);
            ax[0] = ex * __builtin_amdgcn_rcpf(den + 1e-16f);
        }
        unsigned off = (unsigned)(se * (RW * 4));
        sent[wid][lane] = make_uint4(off, __float_as_uint(ax[0]),
                                     off, __float_as_uint(ax[H - 1]));
        __threadfence_block();
#pragma unroll 2
        for (int t = 0; t < cnt; t += G) {
            uint2 en = *(const uint2*)(sbase + 4 * (t + grp));
            float af = __uint_as_float(en.y);
            uint4 u = *(const uint4*)(hflb + en.x);
            f32x2 c;
            c.x = bf16lo(u.x); c.y = bf16hi(u.x); A01 += af * c;
            c.x = bf16lo(u.y); c.y = bf16hi(u.y); A23 += af * c;
            c.x = bf16lo(u.z); c.y = bf16hi(u.z); A45 += af * c;
            c.x = bf16lo(u.w); c.y = bf16hi(u.w); A67 += af * c;
        }
    } else {
        // chunked path (deg > 64) -- statistically never, correctness only
        float psum[H];
#pragma unroll
        for (int h = 0; h < H; ++h) psum[h] = 0.f;
        for (int base = r0; base < r1; base += 64) {
            int i = base + lane;
            bool act = i < r1;
            int s = act ? srcs[i] : 0;
#pragma unroll
            for (int h = 0; h < H; ++h) {
                float sc = lrelu(as_[(size_t)s * H + h] + uad[h]);
                psum[h] += act ? __expf(sc) : 0.f;
            }
        }
        float inv[H];
#pragma unroll
        for (int h = 0; h < H; ++h)
            inv[h] = __builtin_amdgcn_rcpf(wred_sum(psum[h]) + 1e-16f);
        for (int base = r0; base < r1; base += 64) {
            int i = base + lane;
            bool act = i < r1;
            int se = act ? srcs[i] : 0;
            float ax[H];
#pragma unroll
            for (int h = 0; h < H; ++h) {
                float sc = lrelu(as_[(size_t)se * H + h] + uad[h]);
                ax[h] = act ? __expf(sc) * inv[h] : 0.f;
            }
            int cntc = min(64, r1 - base);
            unsigned off = (unsigned)(se * (RW * 4));
            sent[wid][lane] = make_uint4(off, __float_as_uint(ax[0]),
                                         off, __float_as_uint(ax[H - 1]));
            __threadfence_block();
            for (int t = 0; t < cntc; t += G) {
                uint2 en = *(const uint2*)(sbase + 4 * (t + grp));
                float af = __uint_as_float(en.y);
                uint4 u = *(const uint4*)(hflb + en.x);
                f32x2 c;
                c.x = bf16lo(u.x); c.y = bf16hi(u.x); A01 += af * c;
                c.x = bf16lo(u.y); c.y = bf16hi(u.y); A23 += af * c;
                c.x = bf16lo(u.z); c.y = bf16hi(u.z); A45 += af * c;
                c.x = bf16lo(u.w); c.y = bf16hi(u.w); A67 += af * c;
            }
            __threadfence_block();
        }
    }

    // cross-group reduction
#pragma unroll
    for (int o = GL; o < 64; o <<= 1) {
        A01.x += __shfl_xor(A01.x, o); A01.y += __shfl_xor(A01.y, o);
        A23.x += __shfl_xor(A23.x, o); A23.y += __shfl_xor(A23.y, o);
        A45.x += __shfl_xor(A45.x, o); A45.y += __shfl_xor(A45.y, o);
        A67.x += __shfl_xor(A67.x, o); A67.y += __shfl_xor(A67.y, o);
    }
    if (grp == 0) {
        int c0 = 8 * il;
        float4 bA = *(const float4*)(bias + c0);
        float4 bB = *(const float4*)(bias + c0 + 4);
        float v0 = A01.x + bA.x, v1 = A01.y + bA.y, v2 = A23.x + bA.z, v3 = A23.y + bA.w;
        float v4 = A45.x + bB.x, v5 = A45.y + bB.y, v6 = A67.x + bB.z, v7 = A67.y + bB.w;
        if (DO_ELU) {
            v0 = v0 > 0.f ? v0 : expm1f(v0); v1 = v1 > 0.f ? v1 : expm1f(v1);
            v2 = v2 > 0.f ? v2 : expm1f(v2); v3 = v3 > 0.f ? v3 : expm1f(v3);
            v4 = v4 > 0.f ? v4 : expm1f(v4); v5 = v5 > 0.f ? v5 : expm1f(v5);
            v6 = v6 > 0.f ? v6 : expm1f(v6); v7 = v7 > 0.f ? v7 : expm1f(v7);
        }
        if (H == 2) {
            uint4 o;
            o.x = pkbf(v0, v1); o.y = pkbf(v2, v3);
            o.z = pkbf(v4, v5); o.w = pkbf(v6, v7);
            *(uint4*)((unsigned*)outp + (size_t)d * 64 + 4 * il) = o;
        } else {
            *(float4*)((float*)outp + (size_t)d * 64 + c0) = make_float4(v0, v1, v2, v3);
            *(float4*)((float*)outp + (size_t)d * 64 + c0 + 4) = make_float4(v4, v5, v6, v7);
        }
    }
}

extern "C" void kernel_launch(void* const* d_in, const int* in_sizes, int n_in,
                              void* d_out, int out_size, void* d_ws, size_t ws_size,
                              hipStream_t stream) {
    const float* x   = (const float*)d_in[0];
    const int*   ei  = (const int*)d_in[1];
    const float* W1  = (const float*)d_in[2];
    const float* a1s = (const float*)d_in[3];
    const float* a1d = (const float*)d_in[4];
    const float* b1  = (const float*)d_in[5];
    const float* W2  = (const float*)d_in[6];
    const float* a2s = (const float*)d_in[7];
    const float* a2d = (const float*)d_in[8];
    const float* b2  = (const float*)d_in[9];
    float* out = (float*)d_out;

    int N  = in_sizes[0] / 128;
    int E  = in_sizes[1] / 2;
    int Et = E + N;
    int NB = (Et + 4095) / 4096;           // phase-1 blocks
    int nh = 256 * NB;                      // histogram entries

    char* p = (char*)d_ws;
    unsigned short* h1b = (unsigned short*)p;   p += (size_t)N * 128 * 2;
    unsigned short* act1b = (unsigned short*)p; p += (size_t)N * 128 * 2;
    unsigned short* h2b = (unsigned short*)p;   p += (size_t)N * 64 * 2;
    unsigned short* w1b = (unsigned short*)p;   p += 128 * 128 * 2;
    unsigned short* w2b = (unsigned short*)p;   p += 64 * 128 * 2;
    uint2* tmp = (uint2*)p;                p += (size_t)Et * 8;
    int* g_hist = (int*)p;                 p += (size_t)nh * 4;
    int* g_scan = (int*)p;                 p += (size_t)(nh + 1) * 4;
    int* partial = (int*)p;                p += (size_t)((nh + 255) / 256) * 4;
    float* as1 = (float*)p;                p += (size_t)N * 2 * 4;
    float* ad1 = (float*)p;                p += (size_t)N * 2 * 4;
    float* as2 = (float*)p;                p += (size_t)N * 4;
    float* ad2 = (float*)p;                p += (size_t)N * 4;
    int* rowptr = (int*)p;                 p += (size_t)(N + 1) * 4;
    int* srcs = (int*)p;                   p += (size_t)Et * 4;

    // ---- CSR build: no global atomics ----
    int nbs = (nh + 255) / 256;
    k1_hist<<<NB, 256, 0, stream>>>(ei, E, Et, g_hist, NB);
    scan_p1<<<nbs, 256, 0, stream>>>(g_hist, partial, nh);
    scan_p2<<<1, 256, 0, stream>>>(partial, nbs);
    scan_p3g<<<nbs, 256, 0, stream>>>(g_hist, partial, g_scan, nh);
    k3_scatter<<<NB, 256, 0, stream>>>(ei, E, Et, g_scan, tmp, NB);
    csr_finalize<<<256, 256, 0, stream>>>(tmp, g_scan, srcs, rowptr, N, Et, NB);

    // ---- weight casts (single launch) ----
    cast_w<<<12, 256, 0, stream>>>(W1, W2, w1b, w2b);

    // ---- layer 1 (x cast fused into GEMM) ----
    gemm_mfma<128, 2, true><<<(N + 63) / 64, 256, 0, stream>>>(x, w1b, a1s, a1d, h1b, as1, ad1, N);
    gat_agg<2, true><<<(N + 3) / 4, 256, 0, stream>>>(rowptr, srcs, as1, ad1,
                                                      (const unsigned*)h1b, b1, act1b, N);

    // ---- layer 2 ----
    gemm_mfma<64, 1, false><<<(N + 63) / 64, 256, 0, stream>>>(act1b, w2b, a2s, a2d, h2b, as2, ad2, N);
    gat_agg<1, false><<<(N + 3) / 4, 256, 0, stream>>>(rowptr, srcs, as2, ad2,
                                                       (const unsigned*)h2b, b2, out, N);
}